// Round 6
// baseline (211.358 us; speedup 1.0000x reference)
//
#include <hip/hip_runtime.h>
#include <hip/hip_bf16.h>
#include <math.h>

#define NUM_HEADS 16
#define D_KV 64
#define D_MODEL 1024
#define SEQ 2048
#define BATCH 2
#define LOG2E 1.4426950408889634f

using bf16x8 = __attribute__((ext_vector_type(8))) short;
using bf16x4 = __attribute__((ext_vector_type(4))) short;
using f32x4  = __attribute__((ext_vector_type(4))) float;

__device__ inline unsigned short f2bf(float f) {
  union { float f; unsigned int i; } v; v.f = f;
  unsigned int u = v.i;
  return (unsigned short)((u + 0x7FFFu + ((u >> 16) & 1u)) >> 16);
}
__device__ inline unsigned short f2bf_fast(float f) {
  union { float f; unsigned int i; } v; v.f = f;
  return (unsigned short)((v.i + 0x8000u) >> 16);
}

#if __has_builtin(__builtin_amdgcn_exp2f)
#define EXP2(x) __builtin_amdgcn_exp2f(x)
#else
#define EXP2(x) __expf((x) * 0.6931471805599453f)
#endif

__device__ inline unsigned int pk_bf16(float a, float b) {
#if __has_builtin(__builtin_amdgcn_cvt_pk_bf16_f32)
  auto v = __builtin_amdgcn_cvt_pk_bf16_f32(a, b);
  unsigned int u; __builtin_memcpy(&u, &v, 4);
  return u;
#else
  return ((unsigned int)f2bf_fast(b) << 16) | f2bf_fast(a);
#endif
}

// async global->LDS, 16 B per lane (dest lane-contiguous)
__device__ inline void gld_lds16(const unsigned short* g, unsigned short* l) {
  __builtin_amdgcn_global_load_lds(
      (const __attribute__((address_space(1))) unsigned int*)g,
      (__attribute__((address_space(3))) unsigned int*)l, 16, 0, 0);
}

// ---------------- fused prep: X convert + 4 weight transposes + bias table ----------------
// R12: bias table 16 blocks (one per head) instead of 1 block doing all heads.
__global__ __launch_bounds__(256) void prep_kernel(const float* __restrict__ X,
                                                   const float* __restrict__ W0,
                                                   const float* __restrict__ W1,
                                                   const float* __restrict__ W2,
                                                   const float* __restrict__ W3,
                                                   const float* __restrict__ tbl,
                                                   unsigned short* __restrict__ xbf,
                                                   unsigned short* __restrict__ wt,
                                                   float* __restrict__ biasF) {
  __shared__ __align__(16) unsigned short T[64][72];
  int bid = blockIdx.x;
  int t = threadIdx.x;
  if (bid < 2048) {
    int i = (bid * 256 + t) * 8;
    __align__(16) unsigned short tmp[8];
#pragma unroll
    for (int e = 0; e < 8; e++) tmp[e] = f2bf(X[i + e]);
    *(uint4*)&xbf[i] = *(uint4*)tmp;
  } else if (bid < 3072) {
    int rem = bid - 2048;
    int z = rem >> 8, tid = rem & 255;
    const float* in = (z == 0) ? W0 : (z == 1) ? W1 : (z == 2) ? W2 : W3;
    unsigned short* o = wt + (long)z * 1048576;
    int r0 = (tid & 15) * 64, c0 = (tid >> 4) * 64;
#pragma unroll
    for (int i = 0; i < 2; i++) {
      int c = t + 256 * i; int r = c >> 3, k8 = (c & 7) * 8;
      const float* src = &in[(long)(r0 + r) * 1024 + c0 + k8];
      __align__(16) unsigned short tmp[8];
#pragma unroll
      for (int e = 0; e < 8; e++) tmp[e] = f2bf(src[e]);
      *(uint4*)&T[r][k8] = *(uint4*)tmp;
    }
    __syncthreads();
#pragma unroll
    for (int i = 0; i < 2; i++) {
      int c = t + 256 * i; int r = c >> 3, k8 = (c & 7) * 8;
      __align__(16) unsigned short tmp[8];
#pragma unroll
      for (int e = 0; e < 8; e++) tmp[e] = T[k8 + e][r];
      *(uint4*)&o[(long)(c0 + r) * 1024 + r0 + k8] = *(uint4*)tmp;
    }
  } else {
    int h = bid - 3072;   // one block per head
#pragma unroll
    for (int ii = 0; ii < 16; ii++) {
      int idx = t + 256 * ii;
      if (idx >= 4095) break;
      int rel = idx - 2047;
      int bucket = (rel > 0) ? 16 : 0;
      int rp = rel < 0 ? -rel : rel;
      int add;
      if (rp < 8) add = rp;
      else {
        int rl = 8 + (int)(logf((float)rp * 0.125f) / logf(16.0f) * 8.0f);
        add = rl < 15 ? rl : 15;
      }
      bucket += add;
      biasF[h * 4096 + idx] = tbl[bucket * 16 + h] * LOG2E;
    }
  }
}

// ---------------- QKV GEMM: C = X(4096x1024) @ Wt(NxK)^T per z, BK=32, dbuf prefetch ----------------
// R12/R13 (T3-minimum, validated R5): dbuf staging + counted s_waitcnt vmcnt(4);
// sched_barrier(0) after each raw s_barrier (s_barrier is not an IR memory fence).
__global__ __launch_bounds__(256) void gemm_kernel(const unsigned short* __restrict__ X,
                                                   const unsigned short* __restrict__ Wt,
                                                   unsigned short* __restrict__ out_b,
                                                   unsigned short* __restrict__ out_vt) {
  __shared__ __align__(16) unsigned short SMEM[128 * 136];   // loop: As|Bs dbuf 32KB; epilogue: C-tile 34.8KB
  unsigned short* As = SMEM;               // [2 buf][128][32]
  unsigned short* Bs = SMEM + 8192;        // [2 buf][128][32]
  const int K = 1024;
  int m0 = blockIdx.x * 128;
  int n0 = blockIdx.y * 128;
  const unsigned short* W = Wt + (long)blockIdx.z * 1048576;
  unsigned short* outq = out_b + (long)blockIdx.z * 4194304;
  float scale = (blockIdx.z == 0) ? LOG2E : 1.0f;
  int t = threadIdx.x;
  int w = t >> 6, l = t & 63;
  int wr = (w >> 1) * 64, wc = (w & 1) * 64;
  int lr = l & 15, lq = l >> 4;
  f32x4 acc[4][4];
#pragma unroll
  for (int i = 0; i < 4; i++)
#pragma unroll
    for (int j = 0; j < 4; j++) acc[i][j] = (f32x4){0.f, 0.f, 0.f, 0.f};

  auto STAGE = [&](int buf, int k0) {
    unsigned short* A = As + buf * 4096;
    unsigned short* B = Bs + buf * 4096;
#pragma unroll
    for (int i = 0; i < 2; i++) {
      int c = t + 256 * i;
      int r = c >> 2, kc = (c & 3) * 8;
      gld_lds16(&X[(long)(m0 + r) * K + k0 + kc], &A[c * 8]);
      gld_lds16(&W[(long)(n0 + r) * K + k0 + kc], &B[c * 8]);
    }
  };

  STAGE(0, 0);
  for (int k0 = 0; k0 < K; k0 += 32) {
    int cur = (k0 >> 5) & 1;
    bool more = k0 + 32 < K;
    if (more) {
      STAGE(cur ^ 1, k0 + 32);
      asm volatile("s_waitcnt vmcnt(4)" ::: "memory");   // cur's 4 loads landed; next 4 in flight
    } else {
      asm volatile("s_waitcnt vmcnt(0)" ::: "memory");
    }
    __builtin_amdgcn_s_barrier();
    __builtin_amdgcn_sched_barrier(0);                   // pin ds_reads below the barrier
    const unsigned short* Ab = As + cur * 4096;
    const unsigned short* Bb = Bs + cur * 4096;
    bf16x8 a[4], b[4];
#pragma unroll
    for (int mi = 0; mi < 4; mi++) a[mi] = *(const bf16x8*)&Ab[(wr + mi * 16 + lr) * 32 + lq * 8];
#pragma unroll
    for (int ni = 0; ni < 4; ni++) b[ni] = *(const bf16x8*)&Bb[(wc + ni * 16 + lr) * 32 + lq * 8];
#pragma unroll
    for (int mi = 0; mi < 4; mi++)
#pragma unroll
      for (int ni = 0; ni < 4; ni++)
        acc[mi][ni] = __builtin_amdgcn_mfma_f32_16x16x32_bf16(a[mi], b[ni], acc[mi][ni], 0, 0, 0);
    asm volatile("s_waitcnt lgkmcnt(0)" ::: "memory");   // my reads of buf cur retired
    __builtin_amdgcn_s_barrier();                        // all waves done -> cur re-stageable
    __builtin_amdgcn_sched_barrier(0);                   // pin next STAGE below the barrier
  }

  if (blockIdx.z == 2) {
    unsigned short* Cs = SMEM;
#pragma unroll
    for (int mi = 0; mi < 4; mi++)
#pragma unroll
      for (int ni = 0; ni < 4; ni++) {
        int nl = wc + ni * 16 + lr;
        int ml = wr + mi * 16 + lq * 4;
        unsigned int s0 = pk_bf16(acc[mi][ni][0], acc[mi][ni][1]);
        unsigned int s1 = pk_bf16(acc[mi][ni][2], acc[mi][ni][3]);
        *(uint2*)&Cs[nl * 136 + ml] = (uint2){s0, s1};
      }
    __syncthreads();
    int b2 = m0 >> 11, sbase = m0 & 2047;
#pragma unroll
    for (int i = 0; i < 8; i++) {
      int c = t + 256 * i;
      int row = c >> 4, ch = c & 15;
      uint4 v = *(const uint4*)&Cs[row * 136 + ch * 8];
      int n = n0 + row, h = n >> 6, d = n & 63;
      *(uint4*)&out_vt[(((long)(b2 * 16 + h) * 64 + d) << 11) + sbase + ch * 8] = v;
    }
  } else {
    unsigned short* Cs = SMEM;
#pragma unroll
    for (int mi = 0; mi < 4; mi++)
#pragma unroll
      for (int ni = 0; ni < 4; ni++)
#pragma unroll
        for (int r = 0; r < 4; r++)
          Cs[(wr + mi * 16 + lq * 4 + r) * 136 + wc + ni * 16 + lr] = f2bf(acc[mi][ni][r] * scale);
    __syncthreads();
    int b2 = m0 >> 11, sbase = m0 & 2047;
#pragma unroll
    for (int i = 0; i < 8; i++) {
      int c = t + 256 * i;
      int row = c >> 4, ch = c & 15;
      uint4 v = *(const uint4*)&Cs[row * 136 + ch * 8];
      int n = n0 + ch * 8, h = n >> 6, d = n & 63;
      *(uint4*)&outq[((long)(b2 * 16 + h) * 2048 + sbase + row) * 64 + d] = v;
    }
  }
}

// ---------------- out-projection GEMM: 64x64 tiles, BK=64, 1024 blocks, dbuf prefetch ----------------
// R12/R13 (validated R5): counted-vmcnt pipeline + sched_barrier fences.
__global__ __launch_bounds__(256) void ogemm_kernel(const unsigned short* __restrict__ X,
                                                    const unsigned short* __restrict__ W,
                                                    float* __restrict__ out) {
  __shared__ __align__(16) unsigned char SMEM[32768];  // staging dbuf 32KB / epilogue fp32 17.4KB
  unsigned short* As = (unsigned short*)SMEM;          // [2 buf][2 ks][64][32]
  unsigned short* Bs = As + 8192;                      // [2 buf][2 ks][64][32]
  float* Csf = (float*)SMEM;
  const int K = 1024;
  int m0 = blockIdx.x * 64;
  int n0 = blockIdx.y * 64;
  int t = threadIdx.x;
  int w = t >> 6, l = t & 63;
  int wr = (w >> 1) * 32, wc = (w & 1) * 32;
  int lr = l & 15, lq = l >> 4;
  f32x4 acc[2][2];
#pragma unroll
  for (int i = 0; i < 2; i++)
#pragma unroll
    for (int j = 0; j < 2; j++) acc[i][j] = (f32x4){0.f, 0.f, 0.f, 0.f};

  auto STAGE = [&](int buf, int k0) {
    unsigned short* A = As + buf * 4096;
    unsigned short* B = Bs + buf * 4096;
#pragma unroll
    for (int i = 0; i < 2; i++) {
      int c = t + 256 * i;               // c*8 == p*2048 + r*32 + kc
      int p = c >> 8, r = (c >> 2) & 63, kc = (c & 3) * 8;
      gld_lds16(&X[(long)(m0 + r) * K + k0 + p * 32 + kc], &A[c * 8]);
      gld_lds16(&W[(long)(n0 + r) * K + k0 + p * 32 + kc], &B[c * 8]);
    }
  };

  STAGE(0, 0);
  for (int k0 = 0; k0 < K; k0 += 64) {
    int cur = (k0 >> 6) & 1;
    bool more = k0 + 64 < K;
    if (more) {
      STAGE(cur ^ 1, k0 + 64);
      asm volatile("s_waitcnt vmcnt(4)" ::: "memory");
    } else {
      asm volatile("s_waitcnt vmcnt(0)" ::: "memory");
    }
    __builtin_amdgcn_s_barrier();
    __builtin_amdgcn_sched_barrier(0);
    const unsigned short* Ab = As + cur * 4096;
    const unsigned short* Bb = Bs + cur * 4096;
    bf16x8 a[2][2], b[2][2];
#pragma unroll
    for (int ks = 0; ks < 2; ks++) {
#pragma unroll
      for (int mi = 0; mi < 2; mi++) a[mi][ks] = *(const bf16x8*)&Ab[ks * 2048 + (wr + mi * 16 + lr) * 32 + lq * 8];
#pragma unroll
      for (int ni = 0; ni < 2; ni++) b[ni][ks] = *(const bf16x8*)&Bb[ks * 2048 + (wc + ni * 16 + lr) * 32 + lq * 8];
    }
#pragma unroll
    for (int ks = 0; ks < 2; ks++)
#pragma unroll
      for (int mi = 0; mi < 2; mi++)
#pragma unroll
        for (int ni = 0; ni < 2; ni++)
          acc[mi][ni] = __builtin_amdgcn_mfma_f32_16x16x32_bf16(a[mi][ks], b[ni][ks], acc[mi][ni], 0, 0, 0);
    asm volatile("s_waitcnt lgkmcnt(0)" ::: "memory");
    __builtin_amdgcn_s_barrier();
    __builtin_amdgcn_sched_barrier(0);
  }

#pragma unroll
  for (int mi = 0; mi < 2; mi++)
#pragma unroll
    for (int ni = 0; ni < 2; ni++)
#pragma unroll
      for (int r = 0; r < 4; r++)
        Csf[(wr + mi * 16 + lq * 4 + r) * 68 + wc + ni * 16 + lr] = acc[mi][ni][r];
  __syncthreads();
#pragma unroll
  for (int i = 0; i < 4; i++) {
    int c = t + 256 * i;
    int row = c >> 4, ch = c & 15;
    float4 v = *(const float4*)&Csf[row * 68 + ch * 4];
    *(float4*)&out[(long)(m0 + row) * 1024 + n0 + ch * 4] = v;
  }
}

// ---------------- flash attention: 512-thread blocks, intra-block K-split ----------------
// R9: P stays in registers (permuted-k contraction); bias splat for saturated buckets.
// R11: V stored in LDS with the P k-permutation BAKED IN (conflict-free b128 V reads).
// R14 (this round): bias table shrunk 2x2176 -> 2x772 floats. Since the splat covers
// all |dq| chunks outside {-128..192}, table reads only touch rel = k-q in [-255,255];
// a q0-INDEPENDENT window biasR2[c][i] = btabF[1663+i+c] (rel in [-384,388)) covers it
// with margin (read idx verified in [129,639]). LDS 54.3KB -> 42.1KB => 3 blocks/CU
// (was 2): +50% resident waves to hide the softmax serial chain (kernel is
// latency-bound: VALU 42 / DS ~similar / MFMA 21, none saturated).
__global__ __launch_bounds__(512) void attn_kernel(const unsigned short* __restrict__ Q,
                                                   const unsigned short* __restrict__ Km,
                                                   const unsigned short* __restrict__ Vt,
                                                   const float* __restrict__ biasF,
                                                   unsigned short* __restrict__ O) {
  __shared__ __align__(16) unsigned short KV[4][4608];  // [0,1]=K par0/1, [2,3]=V par0/1 (64x72)
  __shared__ __align__(16) float biasR2[2][772];
  int q0 = blockIdx.x * 128;
  int bh = blockIdx.y;
  int b_ = bh >> 4, h = bh & 15;
  const unsigned short* Qb = Q  + (long)bh * SEQ * 64;
  const unsigned short* Kb = Km + (long)bh * SEQ * 64;
  const unsigned short* Vb = Vt + (long)bh * 64 * SEQ;
  const float* btabF = biasF + h * 4096;
  int t = threadIdx.x;
  int w = t >> 6, l = t & 63;
  int g = w >> 2, wg = w & 3;
  int lr = l & 15, lq = l >> 4;
  int qw = wg * 32;

  // saturated-bucket constants (rel=+2047 -> bucket 31, rel=-2047 -> bucket 15)
  float bL = btabF[0], bH = btabF[4094];

  // 2 shift-replicated fp32 window copies (q0-independent; even-aligned float2 reads)
  for (int i = t; i < 772; i += 512) {
    biasR2[0][i] = btabF[1663 + i];
    biasR2[1][i] = btabF[1664 + i];
  }

  bf16x8 aq[2][2];
#pragma unroll
  for (int qt = 0; qt < 2; qt++)
#pragma unroll
    for (int ks = 0; ks < 2; ks++)
      aq[qt][ks] = *(const bf16x8*)&Qb[(long)(q0 + qw + qt * 16 + lr) * 64 + ks * 32 + lq * 8];

  int rs = t >> 3, fs = (t & 7) * 8;

  // permuted V write offsets (loop-invariant): thread's 8 contiguous k split into
  // two uint2 groups matching the in-register P k-order.
  int ktpS = (fs >> 5) & 1;
  int q2 = (fs >> 3) & 3;
  int caS = ktpS * 4 + (q2 & 1) * 2;
  int offS = (q2 >> 1) * 4;
  int vo1 = rs * 72 + caS * 8 + offS;
  int vo2 = vo1 + 8;

  uint4 kpa = *(const uint4*)&Kb[(long)rs * 64 + fs];
  uint4 kpb = *(const uint4*)&Kb[(long)(64 + rs) * 64 + fs];
  uint4 vpa = *(const uint4*)&Vb[(long)rs * SEQ + fs];
  uint4 vpb = *(const uint4*)&Vb[(long)rs * SEQ + 64 + fs];
  *(uint4*)&KV[0][rs * 72 + fs] = kpa;
  *(uint4*)&KV[1][rs * 72 + fs] = kpb;
  *(uint2*)&KV[2][vo1] = (uint2){vpa.x, vpa.y};
  *(uint2*)&KV[2][vo2] = (uint2){vpa.z, vpa.w};
  *(uint2*)&KV[3][vo1] = (uint2){vpb.x, vpb.y};
  *(uint2*)&KV[3][vo2] = (uint2){vpb.z, vpb.w};

  f32x4 accO[4][2];   // [dt][qt], O^T C-tiles (row=d, col=q)
  float rsum[2] = {0.f, 0.f};
#pragma unroll
  for (int qt = 0; qt < 2; qt++)
#pragma unroll
    for (int dt = 0; dt < 4; dt++) accO[dt][qt] = (f32x4){0.f, 0.f, 0.f, 0.f};

  // bias index: window idx = pbc2 + k0 + 16*blk + {0..3}; equals btabF[2047 + k - q]
  int vb = 127 + lq * 4 - qw - lr;
  int bj2 = vb & 1;
  const float* brow = biasR2[bj2];
  int pbc2 = vb - bj2 - 16 + 257 - q0;

  for (int i = 0; i < 16; i++) {
    __syncthreads();
    int k0 = (2 * i + g) * 64;
    bool more = i < 15;

    // ---- bias blocks (5 x 2 float2, aligned); constant splat when bucket saturated ----
    float2 bbl[5][2];
    int dq = k0 - q0;
    if (dq >= 218 || dq <= -154) {
      float bc = (dq >= 218) ? bH : bL;
      float2 bc2 = (float2){bc, bc};
#pragma unroll
      for (int m = 0; m < 5; m++) { bbl[m][0] = bc2; bbl[m][1] = bc2; }
    } else {
      int pb = pbc2 + k0;
#pragma unroll
      for (int m = 0; m < 5; m++) {
        bbl[m][0] = *(const float2*)&brow[pb + 16 * m];
        bbl[m][1] = *(const float2*)&brow[pb + 16 * m + 2];
      }
    }

    bf16x8 bk[4][2];
#pragma unroll
    for (int kt = 0; kt < 4; kt++)
#pragma unroll
      for (int ks = 0; ks < 2; ks++)
        bk[kt][ks] = *(const bf16x8*)&KV[g][(kt * 16 + lr) * 72 + ks * 32 + lq * 8];

    if (more) {
      const unsigned short* Kn = Kb + (long)(2 * i + 2) * 64 * 64;
      const unsigned short* Vn = Vb + (2 * i + 2) * 64;
      kpa = *(const uint4*)&Kn[(long)rs * 64 + fs];
      kpb = *(const uint4*)&Kn[(long)(64 + rs) * 64 + fs];
      vpa = *(const uint4*)&Vn[(long)rs * SEQ + fs];
      vpb = *(const uint4*)&Vn[(long)rs * SEQ + 64 + fs];
    }

    // ---- S^T = K Q^T ----
    f32x4 sacc[4][2];
#pragma unroll
    for (int kt = 0; kt < 4; kt++)
#pragma unroll
      for (int qt = 0; qt < 2; qt++) sacc[kt][qt] = (f32x4){0.f, 0.f, 0.f, 0.f};
#pragma unroll
    for (int ks = 0; ks < 2; ks++)
#pragma unroll
      for (int kt = 0; kt < 4; kt++)
#pragma unroll
        for (int qt = 0; qt < 2; qt++)
          sacc[kt][qt] = __builtin_amdgcn_mfma_f32_16x16x32_bf16(bk[kt][ks], aq[qt][ks], sacc[kt][qt], 0, 0, 0);

    // ---- softmax + PV, P entirely in registers ----
#pragma unroll
    for (int ktp = 0; ktp < 2; ktp++) {
      bf16x8 va8[4];
#pragma unroll
      for (int dt = 0; dt < 4; dt++)
        va8[dt] = *(const bf16x8*)&KV[2 + g][(dt * 16 + lr) * 72 + (ktp * 4 + lq) * 8];
#pragma unroll
      for (int qt = 0; qt < 2; qt++) {
        unsigned int u[4];
#pragma unroll
        for (int kth = 0; kth < 2; kth++) {
          int kt = ktp * 2 + kth;
          int blk = kt - qt + 1;
          float p0 = EXP2(sacc[kt][qt][0] + bbl[blk][0].x);
          float p1 = EXP2(sacc[kt][qt][1] + bbl[blk][0].y);
          float p2 = EXP2(sacc[kt][qt][2] + bbl[blk][1].x);
          float p3 = EXP2(sacc[kt][qt][3] + bbl[blk][1].y);
          rsum[qt] += (p0 + p1) + (p2 + p3);
          u[kth * 2]     = pk_bf16(p0, p1);
          u[kth * 2 + 1] = pk_bf16(p2, p3);
        }
        union { unsigned int uu[4]; bf16x8 v; } pbu;
        pbu.uu[0] = u[0]; pbu.uu[1] = u[1]; pbu.uu[2] = u[2]; pbu.uu[3] = u[3];
#pragma unroll
        for (int dt = 0; dt < 4; dt++)
          accO[dt][qt] = __builtin_amdgcn_mfma_f32_16x16x32_bf16(va8[dt], pbu.v, accO[dt][qt], 0, 0, 0);
      }
    }

    __syncthreads();
    if (more) {
      *(uint4*)&KV[0][rs * 72 + fs] = kpa;
      *(uint4*)&KV[1][rs * 72 + fs] = kpb;
      *(uint2*)&KV[2][vo1] = (uint2){vpa.x, vpa.y};
      *(uint2*)&KV[2][vo2] = (uint2){vpa.z, vpa.w};
      *(uint2*)&KV[3][vo1] = (uint2){vpb.x, vpb.y};
      *(uint2*)&KV[3][vo2] = (uint2){vpb.z, vpb.w};
    }
  }

  // reduce row sums across lq quads (lanes share q = l&15)
#pragma unroll
  for (int qt = 0; qt < 2; qt++) {
    rsum[qt] += __shfl_xor(rsum[qt], 16);
    rsum[qt] += __shfl_xor(rsum[qt], 32);
  }

  // ---- merge group partials via LDS overlay on KV ----
  float* mrg = (float*)&KV[0][0];
  int slot = (wg * 64 + l) * 34;
  if (g == 1) {
    float2* mp = (float2*)&mrg[slot];
    int j = 0;
#pragma unroll
    for (int dt = 0; dt < 4; dt++)
#pragma unroll
      for (int qt = 0; qt < 2; qt++) {
        mp[j++] = (float2){accO[dt][qt][0], accO[dt][qt][1]};
        mp[j++] = (float2){accO[dt][qt][2], accO[dt][qt][3]};
      }
    mp[16] = (float2){rsum[0], rsum[1]};
  }
  __syncthreads();
  if (g == 0) {
    const float2* mp = (const float2*)&mrg[slot];
    int j = 0;
#pragma unroll
    for (int dt = 0; dt < 4; dt++)
#pragma unroll
      for (int qt = 0; qt < 2; qt++) {
        float2 a = mp[j++], b2 = mp[j++];
        accO[dt][qt][0] += a.x;  accO[dt][qt][1] += a.y;
        accO[dt][qt][2] += b2.x; accO[dt][qt][3] += b2.y;
      }
    float2 ls = mp[16];
    float rl0 = 1.0f / (rsum[0] + ls.x);
    float rl1 = 1.0f / (rsum[1] + ls.y);
#pragma unroll
    for (int qt = 0; qt < 2; qt++) {
      float rl = qt ? rl1 : rl0;
      int q = q0 + qw + qt * 16 + lr;
#pragma unroll
      for (int dt = 0; dt < 4; dt++) {
        unsigned int s0 = ((unsigned int)f2bf(accO[dt][qt][1] * rl) << 16) | f2bf(accO[dt][qt][0] * rl);
        unsigned int s1 = ((unsigned int)f2bf(accO[dt][qt][3] * rl) << 16) | f2bf(accO[dt][qt][2] * rl);
        *(uint2*)&O[((long)(b_ * SEQ + q)) * 1024 + h * 64 + dt * 16 + lq * 4] = (uint2){s0, s1};
      }
    }
  }
}

extern "C" void kernel_launch(void* const* d_in, const int* in_sizes, int n_in,
                              void* d_out, int out_size, void* d_ws, size_t ws_size,
                              hipStream_t stream) {
  const float* X   = (const float*)d_in[0];
  const float* Wq  = (const float*)d_in[1];
  const float* Wk  = (const float*)d_in[2];
  const float* Wv  = (const float*)d_in[3];
  const float* Wo  = (const float*)d_in[4];
  const float* tbl = (const float*)d_in[5];

  // compact workspace (40.25 MB): o_ws aliases xbf (dead after QKV gemm)
  unsigned short* wt    = (unsigned short*)d_ws;       // 4 x 1M elems
  unsigned short* xbf   = wt + 4 * 1048576;            // X bf16; later reused as attn O
  unsigned short* q_ws  = xbf + 4194304;
  unsigned short* k_ws  = q_ws + 4194304;
  unsigned short* vt_ws = k_ws + 4194304;              // V^T (B,H,64,S), written by gemm z=2
  float* biasF = (float*)(vt_ws + 4194304);            // 16 x 4096 fp32 (log2e-scaled)
  unsigned short* o_ws  = xbf;

  prep_kernel<<<3088, 256, 0, stream>>>(X, Wq, Wk, Wv, Wo, tbl, xbf, wt, biasF);
  gemm_kernel<<<dim3(32, 8, 3), 256, 0, stream>>>(xbf, wt, q_ws, vt_ws);
  attn_kernel<<<dim3(16, 32), 512, 0, stream>>>(q_ws, k_ws, vt_ws, biasF, o_ws);
  ogemm_kernel<<<dim3(64, 16), 256, 0, stream>>>(o_ws, wt + 3 * 1048576, (float*)d_out);
}

// Round 7
// 208.311 us; speedup vs baseline: 1.0146x; 1.0146x over previous
//
#include <hip/hip_runtime.h>
#include <hip/hip_bf16.h>
#include <math.h>

#define NUM_HEADS 16
#define D_KV 64
#define D_MODEL 1024
#define SEQ 2048
#define BATCH 2
#define LOG2E 1.4426950408889634f

using bf16x8 = __attribute__((ext_vector_type(8))) short;
using bf16x4 = __attribute__((ext_vector_type(4))) short;
using f32x4  = __attribute__((ext_vector_type(4))) float;

__device__ inline unsigned short f2bf(float f) {
  union { float f; unsigned int i; } v; v.f = f;
  unsigned int u = v.i;
  return (unsigned short)((u + 0x7FFFu + ((u >> 16) & 1u)) >> 16);
}
__device__ inline unsigned short f2bf_fast(float f) {
  union { float f; unsigned int i; } v; v.f = f;
  return (unsigned short)((v.i + 0x8000u) >> 16);
}

#if __has_builtin(__builtin_amdgcn_exp2f)
#define EXP2(x) __builtin_amdgcn_exp2f(x)
#else
#define EXP2(x) __expf((x) * 0.6931471805599453f)
#endif

__device__ inline unsigned int pk_bf16(float a, float b) {
#if __has_builtin(__builtin_amdgcn_cvt_pk_bf16_f32)
  auto v = __builtin_amdgcn_cvt_pk_bf16_f32(a, b);
  unsigned int u; __builtin_memcpy(&u, &v, 4);
  return u;
#else
  return ((unsigned int)f2bf_fast(b) << 16) | f2bf_fast(a);
#endif
}

// async global->LDS, 16 B per lane (dest lane-contiguous)
__device__ inline void gld_lds16(const unsigned short* g, unsigned short* l) {
  __builtin_amdgcn_global_load_lds(
      (const __attribute__((address_space(1))) unsigned int*)g,
      (__attribute__((address_space(3))) unsigned int*)l, 16, 0, 0);
}

// ---------------- fused prep: X convert + 4 weight transposes + bias table ----------------
__global__ __launch_bounds__(256) void prep_kernel(const float* __restrict__ X,
                                                   const float* __restrict__ W0,
                                                   const float* __restrict__ W1,
                                                   const float* __restrict__ W2,
                                                   const float* __restrict__ W3,
                                                   const float* __restrict__ tbl,
                                                   unsigned short* __restrict__ xbf,
                                                   unsigned short* __restrict__ wt,
                                                   float* __restrict__ biasF) {
  __shared__ __align__(16) unsigned short T[64][72];
  int bid = blockIdx.x;
  int t = threadIdx.x;
  if (bid < 2048) {
    int i = (bid * 256 + t) * 8;
    __align__(16) unsigned short tmp[8];
#pragma unroll
    for (int e = 0; e < 8; e++) tmp[e] = f2bf(X[i + e]);
    *(uint4*)&xbf[i] = *(uint4*)tmp;
  } else if (bid < 3072) {
    int rem = bid - 2048;
    int z = rem >> 8, tid = rem & 255;
    const float* in = (z == 0) ? W0 : (z == 1) ? W1 : (z == 2) ? W2 : W3;
    unsigned short* o = wt + (long)z * 1048576;
    int r0 = (tid & 15) * 64, c0 = (tid >> 4) * 64;
#pragma unroll
    for (int i = 0; i < 2; i++) {
      int c = t + 256 * i; int r = c >> 3, k8 = (c & 7) * 8;
      const float* src = &in[(long)(r0 + r) * 1024 + c0 + k8];
      __align__(16) unsigned short tmp[8];
#pragma unroll
      for (int e = 0; e < 8; e++) tmp[e] = f2bf(src[e]);
      *(uint4*)&T[r][k8] = *(uint4*)tmp;
    }
    __syncthreads();
#pragma unroll
    for (int i = 0; i < 2; i++) {
      int c = t + 256 * i; int r = c >> 3, k8 = (c & 7) * 8;
      __align__(16) unsigned short tmp[8];
#pragma unroll
      for (int e = 0; e < 8; e++) tmp[e] = T[k8 + e][r];
      *(uint4*)&o[(long)(c0 + r) * 1024 + r0 + k8] = *(uint4*)tmp;
    }
  } else {
    int h = bid - 3072;   // one block per head
#pragma unroll
    for (int ii = 0; ii < 16; ii++) {
      int idx = t + 256 * ii;
      if (idx >= 4095) break;
      int rel = idx - 2047;
      int bucket = (rel > 0) ? 16 : 0;
      int rp = rel < 0 ? -rel : rel;
      int add;
      if (rp < 8) add = rp;
      else {
        int rl = 8 + (int)(logf((float)rp * 0.125f) / logf(16.0f) * 8.0f);
        add = rl < 15 ? rl : 15;
      }
      bucket += add;
      biasF[h * 4096 + idx] = tbl[bucket * 16 + h] * LOG2E;
    }
  }
}

// ---------------- QKV GEMM: C = X(4096x1024) @ Wt(NxK)^T per z, BK=32, dbuf prefetch ----------------
// R12/R13 (T3-minimum, validated R5): dbuf staging + counted s_waitcnt vmcnt(4);
// sched_barrier(0) after each raw s_barrier (s_barrier is not an IR memory fence).
__global__ __launch_bounds__(256) void gemm_kernel(const unsigned short* __restrict__ X,
                                                   const unsigned short* __restrict__ Wt,
                                                   unsigned short* __restrict__ out_b,
                                                   unsigned short* __restrict__ out_vt) {
  __shared__ __align__(16) unsigned short SMEM[128 * 136];   // loop: As|Bs dbuf 32KB; epilogue: C-tile 34.8KB
  unsigned short* As = SMEM;               // [2 buf][128][32]
  unsigned short* Bs = SMEM + 8192;        // [2 buf][128][32]
  const int K = 1024;
  int m0 = blockIdx.x * 128;
  int n0 = blockIdx.y * 128;
  const unsigned short* W = Wt + (long)blockIdx.z * 1048576;
  unsigned short* outq = out_b + (long)blockIdx.z * 4194304;
  float scale = (blockIdx.z == 0) ? LOG2E : 1.0f;
  int t = threadIdx.x;
  int w = t >> 6, l = t & 63;
  int wr = (w >> 1) * 64, wc = (w & 1) * 64;
  int lr = l & 15, lq = l >> 4;
  f32x4 acc[4][4];
#pragma unroll
  for (int i = 0; i < 4; i++)
#pragma unroll
    for (int j = 0; j < 4; j++) acc[i][j] = (f32x4){0.f, 0.f, 0.f, 0.f};

  auto STAGE = [&](int buf, int k0) {
    unsigned short* A = As + buf * 4096;
    unsigned short* B = Bs + buf * 4096;
#pragma unroll
    for (int i = 0; i < 2; i++) {
      int c = t + 256 * i;
      int r = c >> 2, kc = (c & 3) * 8;
      gld_lds16(&X[(long)(m0 + r) * K + k0 + kc], &A[c * 8]);
      gld_lds16(&W[(long)(n0 + r) * K + k0 + kc], &B[c * 8]);
    }
  };

  STAGE(0, 0);
  for (int k0 = 0; k0 < K; k0 += 32) {
    int cur = (k0 >> 5) & 1;
    bool more = k0 + 32 < K;
    if (more) {
      STAGE(cur ^ 1, k0 + 32);
      asm volatile("s_waitcnt vmcnt(4)" ::: "memory");   // cur's 4 loads landed; next 4 in flight
    } else {
      asm volatile("s_waitcnt vmcnt(0)" ::: "memory");
    }
    __builtin_amdgcn_s_barrier();
    __builtin_amdgcn_sched_barrier(0);                   // pin ds_reads below the barrier
    const unsigned short* Ab = As + cur * 4096;
    const unsigned short* Bb = Bs + cur * 4096;
    bf16x8 a[4], b[4];
#pragma unroll
    for (int mi = 0; mi < 4; mi++) a[mi] = *(const bf16x8*)&Ab[(wr + mi * 16 + lr) * 32 + lq * 8];
#pragma unroll
    for (int ni = 0; ni < 4; ni++) b[ni] = *(const bf16x8*)&Bb[(wc + ni * 16 + lr) * 32 + lq * 8];
#pragma unroll
    for (int mi = 0; mi < 4; mi++)
#pragma unroll
      for (int ni = 0; ni < 4; ni++)
        acc[mi][ni] = __builtin_amdgcn_mfma_f32_16x16x32_bf16(a[mi], b[ni], acc[mi][ni], 0, 0, 0);
    asm volatile("s_waitcnt lgkmcnt(0)" ::: "memory");   // my reads of buf cur retired
    __builtin_amdgcn_s_barrier();                        // all waves done -> cur re-stageable
    __builtin_amdgcn_sched_barrier(0);                   // pin next STAGE below the barrier
  }

  if (blockIdx.z == 2) {
    unsigned short* Cs = SMEM;
#pragma unroll
    for (int mi = 0; mi < 4; mi++)
#pragma unroll
      for (int ni = 0; ni < 4; ni++) {
        int nl = wc + ni * 16 + lr;
        int ml = wr + mi * 16 + lq * 4;
        unsigned int s0 = pk_bf16(acc[mi][ni][0], acc[mi][ni][1]);
        unsigned int s1 = pk_bf16(acc[mi][ni][2], acc[mi][ni][3]);
        *(uint2*)&Cs[nl * 136 + ml] = (uint2){s0, s1};
      }
    __syncthreads();
    int b2 = m0 >> 11, sbase = m0 & 2047;
#pragma unroll
    for (int i = 0; i < 8; i++) {
      int c = t + 256 * i;
      int row = c >> 4, ch = c & 15;
      uint4 v = *(const uint4*)&Cs[row * 136 + ch * 8];
      int n = n0 + row, h = n >> 6, d = n & 63;
      *(uint4*)&out_vt[(((long)(b2 * 16 + h) * 64 + d) << 11) + sbase + ch * 8] = v;
    }
  } else {
    unsigned short* Cs = SMEM;
#pragma unroll
    for (int mi = 0; mi < 4; mi++)
#pragma unroll
      for (int ni = 0; ni < 4; ni++)
#pragma unroll
        for (int r = 0; r < 4; r++)
          Cs[(wr + mi * 16 + lq * 4 + r) * 136 + wc + ni * 16 + lr] = f2bf(acc[mi][ni][r] * scale);
    __syncthreads();
    int b2 = m0 >> 11, sbase = m0 & 2047;
#pragma unroll
    for (int i = 0; i < 8; i++) {
      int c = t + 256 * i;
      int row = c >> 4, ch = c & 15;
      uint4 v = *(const uint4*)&Cs[row * 136 + ch * 8];
      int n = n0 + ch * 8, h = n >> 6, d = n & 63;
      *(uint4*)&outq[((long)(b2 * 16 + h) * 2048 + sbase + row) * 64 + d] = v;
    }
  }
}

// ---------------- out-projection GEMM: 64x64 tiles, BK=64, 1024 blocks, dbuf prefetch ----------------
// R12/R13 (validated R5): counted-vmcnt pipeline + sched_barrier fences.
__global__ __launch_bounds__(256) void ogemm_kernel(const unsigned short* __restrict__ X,
                                                    const unsigned short* __restrict__ W,
                                                    float* __restrict__ out) {
  __shared__ __align__(16) unsigned char SMEM[32768];  // staging dbuf 32KB / epilogue fp32 17.4KB
  unsigned short* As = (unsigned short*)SMEM;          // [2 buf][2 ks][64][32]
  unsigned short* Bs = As + 8192;                      // [2 buf][2 ks][64][32]
  float* Csf = (float*)SMEM;
  const int K = 1024;
  int m0 = blockIdx.x * 64;
  int n0 = blockIdx.y * 64;
  int t = threadIdx.x;
  int w = t >> 6, l = t & 63;
  int wr = (w >> 1) * 32, wc = (w & 1) * 32;
  int lr = l & 15, lq = l >> 4;
  f32x4 acc[2][2];
#pragma unroll
  for (int i = 0; i < 2; i++)
#pragma unroll
    for (int j = 0; j < 2; j++) acc[i][j] = (f32x4){0.f, 0.f, 0.f, 0.f};

  auto STAGE = [&](int buf, int k0) {
    unsigned short* A = As + buf * 4096;
    unsigned short* B = Bs + buf * 4096;
#pragma unroll
    for (int i = 0; i < 2; i++) {
      int c = t + 256 * i;               // c*8 == p*2048 + r*32 + kc
      int p = c >> 8, r = (c >> 2) & 63, kc = (c & 3) * 8;
      gld_lds16(&X[(long)(m0 + r) * K + k0 + p * 32 + kc], &A[c * 8]);
      gld_lds16(&W[(long)(n0 + r) * K + k0 + p * 32 + kc], &B[c * 8]);
    }
  };

  STAGE(0, 0);
  for (int k0 = 0; k0 < K; k0 += 64) {
    int cur = (k0 >> 6) & 1;
    bool more = k0 + 64 < K;
    if (more) {
      STAGE(cur ^ 1, k0 + 64);
      asm volatile("s_waitcnt vmcnt(4)" ::: "memory");
    } else {
      asm volatile("s_waitcnt vmcnt(0)" ::: "memory");
    }
    __builtin_amdgcn_s_barrier();
    __builtin_amdgcn_sched_barrier(0);
    const unsigned short* Ab = As + cur * 4096;
    const unsigned short* Bb = Bs + cur * 4096;
    bf16x8 a[2][2], b[2][2];
#pragma unroll
    for (int ks = 0; ks < 2; ks++) {
#pragma unroll
      for (int mi = 0; mi < 2; mi++) a[mi][ks] = *(const bf16x8*)&Ab[ks * 2048 + (wr + mi * 16 + lr) * 32 + lq * 8];
#pragma unroll
      for (int ni = 0; ni < 2; ni++) b[ni][ks] = *(const bf16x8*)&Bb[ks * 2048 + (wc + ni * 16 + lr) * 32 + lq * 8];
    }
#pragma unroll
    for (int ks = 0; ks < 2; ks++)
#pragma unroll
      for (int mi = 0; mi < 2; mi++)
#pragma unroll
        for (int ni = 0; ni < 2; ni++)
          acc[mi][ni] = __builtin_amdgcn_mfma_f32_16x16x32_bf16(a[mi][ks], b[ni][ks], acc[mi][ni], 0, 0, 0);
    asm volatile("s_waitcnt lgkmcnt(0)" ::: "memory");
    __builtin_amdgcn_s_barrier();
    __builtin_amdgcn_sched_barrier(0);
  }

#pragma unroll
  for (int mi = 0; mi < 2; mi++)
#pragma unroll
    for (int ni = 0; ni < 2; ni++)
#pragma unroll
      for (int r = 0; r < 4; r++)
        Csf[(wr + mi * 16 + lq * 4 + r) * 68 + wc + ni * 16 + lr] = acc[mi][ni][r];
  __syncthreads();
#pragma unroll
  for (int i = 0; i < 4; i++) {
    int c = t + 256 * i;
    int row = c >> 4, ch = c & 15;
    float4 v = *(const float4*)&Csf[row * 68 + ch * 4];
    *(float4*)&out[(long)(m0 + row) * 1024 + n0 + ch * 4] = v;
  }
}

// ---------------- flash attention: 512-thread blocks, intra-block K-split ----------------
// R9: P stays in registers (permuted-k contraction); bias splat for saturated buckets.
// R11: V stored in LDS with the P k-permutation BAKED IN (conflict-free b128 V reads).
// R14: small q0-independent bias window (2x772). R14 REGRESSED (63.6->75.1us) because
// LDS 42.5KB allowed 3 blocks/CU while grid=512 is exactly 2/CU -> UNEVEN packing
// (3+1 on some CU pairs); the old 54KB footprint was accidentally enforcing balance.
// R15 (this round): KV DOUBLE-BUFFERED [2][4][4608] = 73.7KB + bias 6.2KB = 79.9KB
//   -> (a) 2 blocks/CU LDS-capped again = balanced distribution guaranteed;
//   -> (b) iteration reads buf (i&1), writes tile i+1 to buf (i&1)^1: the mid-loop
//      barrier between "reads done" and "restage" disappears -- ONE barrier/iter
//      (bottom barrier; its per-wave lgkm drain also closes the WAR on the old
//      read buffer for the next iteration's writes).
__global__ __launch_bounds__(512) void attn_kernel(const unsigned short* __restrict__ Q,
                                                   const unsigned short* __restrict__ Km,
                                                   const unsigned short* __restrict__ Vt,
                                                   const float* __restrict__ biasF,
                                                   unsigned short* __restrict__ O) {
  __shared__ __align__(16) unsigned short KV[2][4][4608];  // dbuf x {K g0,K g1,V g0,V g1} (64x72)
  __shared__ __align__(16) float biasR2[2][772];
  int q0 = blockIdx.x * 128;
  int bh = blockIdx.y;
  int b_ = bh >> 4, h = bh & 15;
  const unsigned short* Qb = Q  + (long)bh * SEQ * 64;
  const unsigned short* Kb = Km + (long)bh * SEQ * 64;
  const unsigned short* Vb = Vt + (long)bh * 64 * SEQ;
  const float* btabF = biasF + h * 4096;
  int t = threadIdx.x;
  int w = t >> 6, l = t & 63;
  int g = w >> 2, wg = w & 3;
  int lr = l & 15, lq = l >> 4;
  int qw = wg * 32;

  // saturated-bucket constants (rel=+2047 -> bucket 31, rel=-2047 -> bucket 15)
  float bL = btabF[0], bH = btabF[4094];

  // 2 shift-replicated fp32 window copies (q0-independent; even-aligned float2 reads)
  for (int i = t; i < 772; i += 512) {
    biasR2[0][i] = btabF[1663 + i];
    biasR2[1][i] = btabF[1664 + i];
  }

  bf16x8 aq[2][2];
#pragma unroll
  for (int qt = 0; qt < 2; qt++)
#pragma unroll
    for (int ks = 0; ks < 2; ks++)
      aq[qt][ks] = *(const bf16x8*)&Qb[(long)(q0 + qw + qt * 16 + lr) * 64 + ks * 32 + lq * 8];

  int rs = t >> 3, fs = (t & 7) * 8;

  // permuted V write offsets (loop-invariant): thread's 8 contiguous k split into
  // two uint2 groups matching the in-register P k-order.
  int ktpS = (fs >> 5) & 1;
  int q2 = (fs >> 3) & 3;
  int caS = ktpS * 4 + (q2 & 1) * 2;
  int offS = (q2 >> 1) * 4;
  int vo1 = rs * 72 + caS * 8 + offS;
  int vo2 = vo1 + 8;

  uint4 kpa = *(const uint4*)&Kb[(long)rs * 64 + fs];
  uint4 kpb = *(const uint4*)&Kb[(long)(64 + rs) * 64 + fs];
  uint4 vpa = *(const uint4*)&Vb[(long)rs * SEQ + fs];
  uint4 vpb = *(const uint4*)&Vb[(long)rs * SEQ + 64 + fs];
  *(uint4*)&KV[0][0][rs * 72 + fs] = kpa;
  *(uint4*)&KV[0][1][rs * 72 + fs] = kpb;
  *(uint2*)&KV[0][2][vo1] = (uint2){vpa.x, vpa.y};
  *(uint2*)&KV[0][2][vo2] = (uint2){vpa.z, vpa.w};
  *(uint2*)&KV[0][3][vo1] = (uint2){vpb.x, vpb.y};
  *(uint2*)&KV[0][3][vo2] = (uint2){vpb.z, vpb.w};

  f32x4 accO[4][2];   // [dt][qt], O^T C-tiles (row=d, col=q)
  float rsum[2] = {0.f, 0.f};
#pragma unroll
  for (int qt = 0; qt < 2; qt++)
#pragma unroll
    for (int dt = 0; dt < 4; dt++) accO[dt][qt] = (f32x4){0.f, 0.f, 0.f, 0.f};

  // bias index: window idx = pbc2 + k0 + 16*blk + {0..3}; equals btabF[2047 + k - q]
  int vb = 127 + lq * 4 - qw - lr;
  int bj2 = vb & 1;
  const float* brow = biasR2[bj2];
  int pbc2 = vb - bj2 - 16 + 257 - q0;

  __syncthreads();   // prologue tile visible to all

  for (int i = 0; i < 16; i++) {
    int cur = i & 1;
    int k0 = (2 * i + g) * 64;
    bool more = i < 15;

    // ---- bias blocks (5 x 2 float2, aligned); constant splat when bucket saturated ----
    float2 bbl[5][2];
    int dq = k0 - q0;
    if (dq >= 218 || dq <= -154) {
      float bc = (dq >= 218) ? bH : bL;
      float2 bc2 = (float2){bc, bc};
#pragma unroll
      for (int m = 0; m < 5; m++) { bbl[m][0] = bc2; bbl[m][1] = bc2; }
    } else {
      int pb = pbc2 + k0;
#pragma unroll
      for (int m = 0; m < 5; m++) {
        bbl[m][0] = *(const float2*)&brow[pb + 16 * m];
        bbl[m][1] = *(const float2*)&brow[pb + 16 * m + 2];
      }
    }

    bf16x8 bk[4][2];
#pragma unroll
    for (int kt = 0; kt < 4; kt++)
#pragma unroll
      for (int ks = 0; ks < 2; ks++)
        bk[kt][ks] = *(const bf16x8*)&KV[cur][g][(kt * 16 + lr) * 72 + ks * 32 + lq * 8];

    if (more) {
      const unsigned short* Kn = Kb + (long)(2 * i + 2) * 64 * 64;
      const unsigned short* Vn = Vb + (2 * i + 2) * 64;
      kpa = *(const uint4*)&Kn[(long)rs * 64 + fs];
      kpb = *(const uint4*)&Kn[(long)(64 + rs) * 64 + fs];
      vpa = *(const uint4*)&Vn[(long)rs * SEQ + fs];
      vpb = *(const uint4*)&Vn[(long)rs * SEQ + 64 + fs];
    }

    // ---- S^T = K Q^T ----
    f32x4 sacc[4][2];
#pragma unroll
    for (int kt = 0; kt < 4; kt++)
#pragma unroll
      for (int qt = 0; qt < 2; qt++) sacc[kt][qt] = (f32x4){0.f, 0.f, 0.f, 0.f};
#pragma unroll
    for (int ks = 0; ks < 2; ks++)
#pragma unroll
      for (int kt = 0; kt < 4; kt++)
#pragma unroll
        for (int qt = 0; qt < 2; qt++)
          sacc[kt][qt] = __builtin_amdgcn_mfma_f32_16x16x32_bf16(bk[kt][ks], aq[qt][ks], sacc[kt][qt], 0, 0, 0);

    // ---- softmax + PV, P entirely in registers ----
#pragma unroll
    for (int ktp = 0; ktp < 2; ktp++) {
      bf16x8 va8[4];
#pragma unroll
      for (int dt = 0; dt < 4; dt++)
        va8[dt] = *(const bf16x8*)&KV[cur][2 + g][(dt * 16 + lr) * 72 + (ktp * 4 + lq) * 8];
#pragma unroll
      for (int qt = 0; qt < 2; qt++) {
        unsigned int u[4];
#pragma unroll
        for (int kth = 0; kth < 2; kth++) {
          int kt = ktp * 2 + kth;
          int blk = kt - qt + 1;
          float p0 = EXP2(sacc[kt][qt][0] + bbl[blk][0].x);
          float p1 = EXP2(sacc[kt][qt][1] + bbl[blk][0].y);
          float p2 = EXP2(sacc[kt][qt][2] + bbl[blk][1].x);
          float p3 = EXP2(sacc[kt][qt][3] + bbl[blk][1].y);
          rsum[qt] += (p0 + p1) + (p2 + p3);
          u[kth * 2]     = pk_bf16(p0, p1);
          u[kth * 2 + 1] = pk_bf16(p2, p3);
        }
        union { unsigned int uu[4]; bf16x8 v; } pbu;
        pbu.uu[0] = u[0]; pbu.uu[1] = u[1]; pbu.uu[2] = u[2]; pbu.uu[3] = u[3];
#pragma unroll
        for (int dt = 0; dt < 4; dt++)
          accO[dt][qt] = __builtin_amdgcn_mfma_f32_16x16x32_bf16(va8[dt], pbu.v, accO[dt][qt], 0, 0, 0);
      }
    }

    // write NEXT tile into the other buffer (no reader of it this iteration)
    if (more) {
      int nxt = cur ^ 1;
      *(uint4*)&KV[nxt][0][rs * 72 + fs] = kpa;
      *(uint4*)&KV[nxt][1][rs * 72 + fs] = kpb;
      *(uint2*)&KV[nxt][2][vo1] = (uint2){vpa.x, vpa.y};
      *(uint2*)&KV[nxt][2][vo2] = (uint2){vpa.z, vpa.w};
      *(uint2*)&KV[nxt][3][vo1] = (uint2){vpb.x, vpb.y};
      *(uint2*)&KV[nxt][3][vo2] = (uint2){vpb.z, vpb.w};
    }
    __syncthreads();   // single barrier: next-buf writes visible; my reads retired
  }

  // reduce row sums across lq quads (lanes share q = l&15)
#pragma unroll
  for (int qt = 0; qt < 2; qt++) {
    rsum[qt] += __shfl_xor(rsum[qt], 16);
    rsum[qt] += __shfl_xor(rsum[qt], 32);
  }

  // ---- merge group partials via LDS overlay on KV buf0 ----
  float* mrg = (float*)&KV[0][0][0];
  int slot = (wg * 64 + l) * 34;
  if (g == 1) {
    float2* mp = (float2*)&mrg[slot];
    int j = 0;
#pragma unroll
    for (int dt = 0; dt < 4; dt++)
#pragma unroll
      for (int qt = 0; qt < 2; qt++) {
        mp[j++] = (float2){accO[dt][qt][0], accO[dt][qt][1]};
        mp[j++] = (float2){accO[dt][qt][2], accO[dt][qt][3]};
      }
    mp[16] = (float2){rsum[0], rsum[1]};
  }
  __syncthreads();
  if (g == 0) {
    const float2* mp = (const float2*)&mrg[slot];
    int j = 0;
#pragma unroll
    for (int dt = 0; dt < 4; dt++)
#pragma unroll
      for (int qt = 0; qt < 2; qt++) {
        float2 a = mp[j++], b2 = mp[j++];
        accO[dt][qt][0] += a.x;  accO[dt][qt][1] += a.y;
        accO[dt][qt][2] += b2.x; accO[dt][qt][3] += b2.y;
      }
    float2 ls = mp[16];
    float rl0 = 1.0f / (rsum[0] + ls.x);
    float rl1 = 1.0f / (rsum[1] + ls.y);
#pragma unroll
    for (int qt = 0; qt < 2; qt++) {
      float rl = qt ? rl1 : rl0;
      int q = q0 + qw + qt * 16 + lr;
#pragma unroll
      for (int dt = 0; dt < 4; dt++) {
        unsigned int s0 = ((unsigned int)f2bf(accO[dt][qt][1] * rl) << 16) | f2bf(accO[dt][qt][0] * rl);
        unsigned int s1 = ((unsigned int)f2bf(accO[dt][qt][3] * rl) << 16) | f2bf(accO[dt][qt][2] * rl);
        *(uint2*)&O[((long)(b_ * SEQ + q)) * 1024 + h * 64 + dt * 16 + lq * 4] = (uint2){s0, s1};
      }
    }
  }
}

extern "C" void kernel_launch(void* const* d_in, const int* in_sizes, int n_in,
                              void* d_out, int out_size, void* d_ws, size_t ws_size,
                              hipStream_t stream) {
  const float* X   = (const float*)d_in[0];
  const float* Wq  = (const float*)d_in[1];
  const float* Wk  = (const float*)d_in[2];
  const float* Wv  = (const float*)d_in[3];
  const float* Wo  = (const float*)d_in[4];
  const float* tbl = (const float*)d_in[5];

  // compact workspace (40.25 MB): o_ws aliases xbf (dead after QKV gemm)
  unsigned short* wt    = (unsigned short*)d_ws;       // 4 x 1M elems
  unsigned short* xbf   = wt + 4 * 1048576;            // X bf16; later reused as attn O
  unsigned short* q_ws  = xbf + 4194304;
  unsigned short* k_ws  = q_ws + 4194304;
  unsigned short* vt_ws = k_ws + 4194304;              // V^T (B,H,64,S), written by gemm z=2
  float* biasF = (float*)(vt_ws + 4194304);            // 16 x 4096 fp32 (log2e-scaled)
  unsigned short* o_ws  = xbf;

  prep_kernel<<<3088, 256, 0, stream>>>(X, Wq, Wk, Wv, Wo, tbl, xbf, wt, biasF);
  gemm_kernel<<<dim3(32, 8, 3), 256, 0, stream>>>(xbf, wt, q_ws, vt_ws);
  attn_kernel<<<dim3(16, 32), 512, 0, stream>>>(q_ws, k_ws, vt_ws, biasF, o_ws);
  ogemm_kernel<<<dim3(64, 16), 256, 0, stream>>>(o_ws, wt + 3 * 1048576, (float*)d_out);
}

// Round 8
// 197.185 us; speedup vs baseline: 1.0719x; 1.0564x over previous
//
#include <hip/hip_runtime.h>
#include <hip/hip_bf16.h>
#include <math.h>

#define NUM_HEADS 16
#define D_KV 64
#define D_MODEL 1024
#define SEQ 2048
#define BATCH 2
#define LOG2E 1.4426950408889634f

using bf16x8 = __attribute__((ext_vector_type(8))) short;
using bf16x4 = __attribute__((ext_vector_type(4))) short;
using f32x4  = __attribute__((ext_vector_type(4))) float;

__device__ inline unsigned short f2bf(float f) {
  union { float f; unsigned int i; } v; v.f = f;
  unsigned int u = v.i;
  return (unsigned short)((u + 0x7FFFu + ((u >> 16) & 1u)) >> 16);
}
__device__ inline unsigned short f2bf_fast(float f) {
  union { float f; unsigned int i; } v; v.f = f;
  return (unsigned short)((v.i + 0x8000u) >> 16);
}

#if __has_builtin(__builtin_amdgcn_exp2f)
#define EXP2(x) __builtin_amdgcn_exp2f(x)
#else
#define EXP2(x) __expf((x) * 0.6931471805599453f)
#endif

__device__ inline unsigned int pk_bf16(float a, float b) {
#if __has_builtin(__builtin_amdgcn_cvt_pk_bf16_f32)
  auto v = __builtin_amdgcn_cvt_pk_bf16_f32(a, b);
  unsigned int u; __builtin_memcpy(&u, &v, 4);
  return u;
#else
  return ((unsigned int)f2bf_fast(b) << 16) | f2bf_fast(a);
#endif
}

// async global->LDS, 16 B per lane (dest lane-contiguous)
__device__ inline void gld_lds16(const unsigned short* g, unsigned short* l) {
  __builtin_amdgcn_global_load_lds(
      (const __attribute__((address_space(1))) unsigned int*)g,
      (__attribute__((address_space(3))) unsigned int*)l, 16, 0, 0);
}

// ---------------- fused prep: X convert + 4 weight transposes + bias table ----------------
__global__ __launch_bounds__(256) void prep_kernel(const float* __restrict__ X,
                                                   const float* __restrict__ W0,
                                                   const float* __restrict__ W1,
                                                   const float* __restrict__ W2,
                                                   const float* __restrict__ W3,
                                                   const float* __restrict__ tbl,
                                                   unsigned short* __restrict__ xbf,
                                                   unsigned short* __restrict__ wt,
                                                   float* __restrict__ biasF) {
  __shared__ __align__(16) unsigned short T[64][72];
  int bid = blockIdx.x;
  int t = threadIdx.x;
  if (bid < 2048) {
    int i = (bid * 256 + t) * 8;
    __align__(16) unsigned short tmp[8];
#pragma unroll
    for (int e = 0; e < 8; e++) tmp[e] = f2bf(X[i + e]);
    *(uint4*)&xbf[i] = *(uint4*)tmp;
  } else if (bid < 3072) {
    int rem = bid - 2048;
    int z = rem >> 8, tid = rem & 255;
    const float* in = (z == 0) ? W0 : (z == 1) ? W1 : (z == 2) ? W2 : W3;
    unsigned short* o = wt + (long)z * 1048576;
    int r0 = (tid & 15) * 64, c0 = (tid >> 4) * 64;
#pragma unroll
    for (int i = 0; i < 2; i++) {
      int c = t + 256 * i; int r = c >> 3, k8 = (c & 7) * 8;
      const float* src = &in[(long)(r0 + r) * 1024 + c0 + k8];
      __align__(16) unsigned short tmp[8];
#pragma unroll
      for (int e = 0; e < 8; e++) tmp[e] = f2bf(src[e]);
      *(uint4*)&T[r][k8] = *(uint4*)tmp;
    }
    __syncthreads();
#pragma unroll
    for (int i = 0; i < 2; i++) {
      int c = t + 256 * i; int r = c >> 3, k8 = (c & 7) * 8;
      __align__(16) unsigned short tmp[8];
#pragma unroll
      for (int e = 0; e < 8; e++) tmp[e] = T[k8 + e][r];
      *(uint4*)&o[(long)(c0 + r) * 1024 + r0 + k8] = *(uint4*)tmp;
    }
  } else {
    int h = bid - 3072;   // one block per head
#pragma unroll
    for (int ii = 0; ii < 16; ii++) {
      int idx = t + 256 * ii;
      if (idx >= 4095) break;
      int rel = idx - 2047;
      int bucket = (rel > 0) ? 16 : 0;
      int rp = rel < 0 ? -rel : rel;
      int add;
      if (rp < 8) add = rp;
      else {
        int rl = 8 + (int)(logf((float)rp * 0.125f) / logf(16.0f) * 8.0f);
        add = rl < 15 ? rl : 15;
      }
      bucket += add;
      biasF[h * 4096 + idx] = tbl[bucket * 16 + h] * LOG2E;
    }
  }
}

// ---------------- QKV GEMM: C = X(4096x1024) @ Wt(NxK)^T per z, BK=32, dbuf prefetch ----------------
// R12/R13 (T3-minimum, validated R5): dbuf staging + counted s_waitcnt vmcnt(4);
// sched_barrier(0) after each raw s_barrier (s_barrier is not an IR memory fence).
__global__ __launch_bounds__(256) void gemm_kernel(const unsigned short* __restrict__ X,
                                                   const unsigned short* __restrict__ Wt,
                                                   unsigned short* __restrict__ out_b,
                                                   unsigned short* __restrict__ out_vt) {
  __shared__ __align__(16) unsigned short SMEM[128 * 136];   // loop: As|Bs dbuf 32KB; epilogue: C-tile 34.8KB
  unsigned short* As = SMEM;               // [2 buf][128][32]
  unsigned short* Bs = SMEM + 8192;        // [2 buf][128][32]
  const int K = 1024;
  int m0 = blockIdx.x * 128;
  int n0 = blockIdx.y * 128;
  const unsigned short* W = Wt + (long)blockIdx.z * 1048576;
  unsigned short* outq = out_b + (long)blockIdx.z * 4194304;
  float scale = (blockIdx.z == 0) ? LOG2E : 1.0f;
  int t = threadIdx.x;
  int w = t >> 6, l = t & 63;
  int wr = (w >> 1) * 64, wc = (w & 1) * 64;
  int lr = l & 15, lq = l >> 4;
  f32x4 acc[4][4];
#pragma unroll
  for (int i = 0; i < 4; i++)
#pragma unroll
    for (int j = 0; j < 4; j++) acc[i][j] = (f32x4){0.f, 0.f, 0.f, 0.f};

  auto STAGE = [&](int buf, int k0) {
    unsigned short* A = As + buf * 4096;
    unsigned short* B = Bs + buf * 4096;
#pragma unroll
    for (int i = 0; i < 2; i++) {
      int c = t + 256 * i;
      int r = c >> 2, kc = (c & 3) * 8;
      gld_lds16(&X[(long)(m0 + r) * K + k0 + kc], &A[c * 8]);
      gld_lds16(&W[(long)(n0 + r) * K + k0 + kc], &B[c * 8]);
    }
  };

  STAGE(0, 0);
  for (int k0 = 0; k0 < K; k0 += 32) {
    int cur = (k0 >> 5) & 1;
    bool more = k0 + 32 < K;
    if (more) {
      STAGE(cur ^ 1, k0 + 32);
      asm volatile("s_waitcnt vmcnt(4)" ::: "memory");   // cur's 4 loads landed; next 4 in flight
    } else {
      asm volatile("s_waitcnt vmcnt(0)" ::: "memory");
    }
    __builtin_amdgcn_s_barrier();
    __builtin_amdgcn_sched_barrier(0);                   // pin ds_reads below the barrier
    const unsigned short* Ab = As + cur * 4096;
    const unsigned short* Bb = Bs + cur * 4096;
    bf16x8 a[4], b[4];
#pragma unroll
    for (int mi = 0; mi < 4; mi++) a[mi] = *(const bf16x8*)&Ab[(wr + mi * 16 + lr) * 32 + lq * 8];
#pragma unroll
    for (int ni = 0; ni < 4; ni++) b[ni] = *(const bf16x8*)&Bb[(wc + ni * 16 + lr) * 32 + lq * 8];
#pragma unroll
    for (int mi = 0; mi < 4; mi++)
#pragma unroll
      for (int ni = 0; ni < 4; ni++)
        acc[mi][ni] = __builtin_amdgcn_mfma_f32_16x16x32_bf16(a[mi], b[ni], acc[mi][ni], 0, 0, 0);
    asm volatile("s_waitcnt lgkmcnt(0)" ::: "memory");   // my reads of buf cur retired
    __builtin_amdgcn_s_barrier();                        // all waves done -> cur re-stageable
    __builtin_amdgcn_sched_barrier(0);                   // pin next STAGE below the barrier
  }

  if (blockIdx.z == 2) {
    unsigned short* Cs = SMEM;
#pragma unroll
    for (int mi = 0; mi < 4; mi++)
#pragma unroll
      for (int ni = 0; ni < 4; ni++) {
        int nl = wc + ni * 16 + lr;
        int ml = wr + mi * 16 + lq * 4;
        unsigned int s0 = pk_bf16(acc[mi][ni][0], acc[mi][ni][1]);
        unsigned int s1 = pk_bf16(acc[mi][ni][2], acc[mi][ni][3]);
        *(uint2*)&Cs[nl * 136 + ml] = (uint2){s0, s1};
      }
    __syncthreads();
    int b2 = m0 >> 11, sbase = m0 & 2047;
#pragma unroll
    for (int i = 0; i < 8; i++) {
      int c = t + 256 * i;
      int row = c >> 4, ch = c & 15;
      uint4 v = *(const uint4*)&Cs[row * 136 + ch * 8];
      int n = n0 + row, h = n >> 6, d = n & 63;
      *(uint4*)&out_vt[(((long)(b2 * 16 + h) * 64 + d) << 11) + sbase + ch * 8] = v;
    }
  } else {
    unsigned short* Cs = SMEM;
#pragma unroll
    for (int mi = 0; mi < 4; mi++)
#pragma unroll
      for (int ni = 0; ni < 4; ni++)
#pragma unroll
        for (int r = 0; r < 4; r++)
          Cs[(wr + mi * 16 + lq * 4 + r) * 136 + wc + ni * 16 + lr] = f2bf(acc[mi][ni][r] * scale);
    __syncthreads();
    int b2 = m0 >> 11, sbase = m0 & 2047;
#pragma unroll
    for (int i = 0; i < 8; i++) {
      int c = t + 256 * i;
      int row = c >> 4, ch = c & 15;
      uint4 v = *(const uint4*)&Cs[row * 136 + ch * 8];
      int n = n0 + ch * 8, h = n >> 6, d = n & 63;
      *(uint4*)&outq[((long)(b2 * 16 + h) * 2048 + sbase + row) * 64 + d] = v;
    }
  }
}

// ---------------- out-projection GEMM: 128x64 tiles, BK=64, 512 blocks (2/CU), dbuf ----------------
// R16: tile 64x64 -> 128x64 (16 MFMAs per wave per K-step vs 8 -- doubles MFMA:staging
// ratio), same validated counted-vmcnt pipeline (now vmcnt(6): 6 loads/thread/stage).
// LDS padded to 56KB so exactly 2 blocks/CU fit (grid=512=2/CU, balanced).
__global__ __launch_bounds__(256) void ogemm_kernel(const unsigned short* __restrict__ X,
                                                    const unsigned short* __restrict__ W,
                                                    float* __restrict__ out) {
  __shared__ __align__(16) unsigned char SMEM[57344];  // staging dbuf 48KB (pad->2 blk/CU) / epilogue 17.4KB
  unsigned short* As = (unsigned short*)SMEM;          // [2 buf][2 ks][128][32]
  unsigned short* Bs = As + 16384;                     // [2 buf][2 ks][64][32]
  float* Csf = (float*)SMEM;                           // [64][68]
  const int K = 1024;
  int m0 = blockIdx.x * 128;
  int n0 = blockIdx.y * 64;
  int t = threadIdx.x;
  int w = t >> 6, l = t & 63;
  int wr = (w >> 1) * 64, wc = (w & 1) * 32;
  int lr = l & 15, lq = l >> 4;
  f32x4 acc[4][2];
#pragma unroll
  for (int i = 0; i < 4; i++)
#pragma unroll
    for (int j = 0; j < 2; j++) acc[i][j] = (f32x4){0.f, 0.f, 0.f, 0.f};

  auto STAGE = [&](int buf, int k0) {
    unsigned short* A = As + buf * 8192;
    unsigned short* B = Bs + buf * 4096;
#pragma unroll
    for (int i = 0; i < 4; i++) {
      int c = t + 256 * i;                       // A: c*8 == p*4096 + r*32 + kc
      int p = c >> 9, r = (c >> 2) & 127, kc = (c & 3) * 8;
      gld_lds16(&X[(long)(m0 + r) * K + k0 + p * 32 + kc], &A[c * 8]);
    }
#pragma unroll
    for (int i = 0; i < 2; i++) {
      int c = t + 256 * i;                       // B: c*8 == p*2048 + r*32 + kc
      int p = c >> 8, r = (c >> 2) & 63, kc = (c & 3) * 8;
      gld_lds16(&W[(long)(n0 + r) * K + k0 + p * 32 + kc], &B[c * 8]);
    }
  };

  STAGE(0, 0);
  for (int k0 = 0; k0 < K; k0 += 64) {
    int cur = (k0 >> 6) & 1;
    bool more = k0 + 64 < K;
    if (more) {
      STAGE(cur ^ 1, k0 + 64);
      asm volatile("s_waitcnt vmcnt(6)" ::: "memory");   // cur's 6 landed; next 6 in flight
    } else {
      asm volatile("s_waitcnt vmcnt(0)" ::: "memory");
    }
    __builtin_amdgcn_s_barrier();
    __builtin_amdgcn_sched_barrier(0);
    const unsigned short* Ab = As + cur * 8192;
    const unsigned short* Bb = Bs + cur * 4096;
    bf16x8 a[4][2], b[2][2];
#pragma unroll
    for (int ks = 0; ks < 2; ks++) {
#pragma unroll
      for (int mi = 0; mi < 4; mi++) a[mi][ks] = *(const bf16x8*)&Ab[ks * 4096 + (wr + mi * 16 + lr) * 32 + lq * 8];
#pragma unroll
      for (int ni = 0; ni < 2; ni++) b[ni][ks] = *(const bf16x8*)&Bb[ks * 2048 + (wc + ni * 16 + lr) * 32 + lq * 8];
    }
#pragma unroll
    for (int ks = 0; ks < 2; ks++)
#pragma unroll
      for (int mi = 0; mi < 4; mi++)
#pragma unroll
        for (int ni = 0; ni < 2; ni++)
          acc[mi][ni] = __builtin_amdgcn_mfma_f32_16x16x32_bf16(a[mi][ks], b[ni][ks], acc[mi][ni], 0, 0, 0);
    asm volatile("s_waitcnt lgkmcnt(0)" ::: "memory");
    __builtin_amdgcn_s_barrier();
    __builtin_amdgcn_sched_barrier(0);
  }

  // epilogue: two 64-row half-tiles through fp32 LDS
#pragma unroll
  for (int p = 0; p < 2; p++) {
    if (p) __syncthreads();
    if ((w >> 1) == p) {
#pragma unroll
      for (int mi = 0; mi < 4; mi++)
#pragma unroll
        for (int ni = 0; ni < 2; ni++)
#pragma unroll
          for (int r = 0; r < 4; r++)
            Csf[(mi * 16 + lq * 4 + r) * 68 + wc + ni * 16 + lr] = acc[mi][ni][r];
    }
    __syncthreads();
#pragma unroll
    for (int i = 0; i < 4; i++) {
      int c = t + 256 * i;
      int row = c >> 4, ch = c & 15;
      float4 v = *(const float4*)&Csf[row * 68 + ch * 4];
      *(float4*)&out[(long)(m0 + p * 64 + row) * 1024 + n0 + ch * 4] = v;
    }
  }
}

// ---------------- flash attention: 512-thread blocks, intra-block K-split ----------------
// EXACT R5 revert (measured 63.6us there). R6/R7's bias-window + dbuf experiments both
// regressed (75-77us) for reasons not yet attributed; restoring the measured-good state.
// R9: P stays in registers (permuted-k contraction); bias splat for saturated buckets.
// R11: V stored in LDS with the P k-permutation BAKED IN (conflict-free b128 V reads).
__global__ __launch_bounds__(512) void attn_kernel(const unsigned short* __restrict__ Q,
                                                   const unsigned short* __restrict__ Km,
                                                   const unsigned short* __restrict__ Vt,
                                                   const float* __restrict__ biasF,
                                                   unsigned short* __restrict__ O) {
  __shared__ __align__(16) unsigned short KV[4][4608];  // [0,1]=K par0/1, [2,3]=V par0/1 (64x72)
  __shared__ __align__(16) float biasRf[2][2176];
  int q0 = blockIdx.x * 128;
  int bh = blockIdx.y;
  int b_ = bh >> 4, h = bh & 15;
  const unsigned short* Qb = Q  + (long)bh * SEQ * 64;
  const unsigned short* Kb = Km + (long)bh * SEQ * 64;
  const unsigned short* Vb = Vt + (long)bh * 64 * SEQ;
  const float* btabF = biasF + h * 4096;
  int t = threadIdx.x;
  int w = t >> 6, l = t & 63;
  int g = w >> 2, wg = w & 3;
  int lr = l & 15, lq = l >> 4;
  int qw = wg * 32;

  // saturated-bucket constants (rel=+2047 -> bucket 31, rel=-2047 -> bucket 15)
  float bL = btabF[0], bH = btabF[4094];

  // 2 shift-replicated fp32 bias copies (even-aligned float2 reads later)
  int gbase = 1920 - q0;
  for (int i = t; i < 2176; i += 512) {
    int g0 = gbase + i;     if (g0 > 4094) g0 = 4094;
    int g1 = gbase + i + 1; if (g1 > 4094) g1 = 4094;
    biasRf[0][i] = btabF[g0];
    biasRf[1][i] = btabF[g1];
  }

  bf16x8 aq[2][2];
#pragma unroll
  for (int qt = 0; qt < 2; qt++)
#pragma unroll
    for (int ks = 0; ks < 2; ks++)
      aq[qt][ks] = *(const bf16x8*)&Qb[(long)(q0 + qw + qt * 16 + lr) * 64 + ks * 32 + lq * 8];

  int rs = t >> 3, fs = (t & 7) * 8;

  // permuted V write offsets (loop-invariant): thread's 8 contiguous k split into
  // two uint2 groups matching the in-register P k-order.
  int ktpS = (fs >> 5) & 1;
  int q2 = (fs >> 3) & 3;
  int caS = ktpS * 4 + (q2 & 1) * 2;
  int offS = (q2 >> 1) * 4;
  int vo1 = rs * 72 + caS * 8 + offS;
  int vo2 = vo1 + 8;

  uint4 kpa = *(const uint4*)&Kb[(long)rs * 64 + fs];
  uint4 kpb = *(const uint4*)&Kb[(long)(64 + rs) * 64 + fs];
  uint4 vpa = *(const uint4*)&Vb[(long)rs * SEQ + fs];
  uint4 vpb = *(const uint4*)&Vb[(long)rs * SEQ + 64 + fs];
  *(uint4*)&KV[0][rs * 72 + fs] = kpa;
  *(uint4*)&KV[1][rs * 72 + fs] = kpb;
  *(uint2*)&KV[2][vo1] = (uint2){vpa.x, vpa.y};
  *(uint2*)&KV[2][vo2] = (uint2){vpa.z, vpa.w};
  *(uint2*)&KV[3][vo1] = (uint2){vpb.x, vpb.y};
  *(uint2*)&KV[3][vo2] = (uint2){vpb.z, vpb.w};

  f32x4 accO[4][2];   // [dt][qt], O^T C-tiles (row=d, col=q)
  float rsum[2] = {0.f, 0.f};
#pragma unroll
  for (int qt = 0; qt < 2; qt++)
#pragma unroll
    for (int dt = 0; dt < 4; dt++) accO[dt][qt] = (f32x4){0.f, 0.f, 0.f, 0.f};

  // bias index: global idx = vb + k0 + kt*16 - qt*16 + r
  int vb = 127 + lq * 4 - qw - lr;
  int bj2 = vb & 1;
  const float* brow = biasRf[bj2];
  int pbc = vb - bj2 - 16;

  for (int i = 0; i < 16; i++) {
    __syncthreads();
    int k0 = (2 * i + g) * 64;
    bool more = i < 15;

    // ---- bias blocks (5 x 2 float2, aligned); constant splat when bucket saturated ----
    float2 bbl[5][2];
    int dq = k0 - q0;
    if (dq >= 218 || dq <= -154) {
      float bc = (dq >= 218) ? bH : bL;
      float2 bc2 = (float2){bc, bc};
#pragma unroll
      for (int m = 0; m < 5; m++) { bbl[m][0] = bc2; bbl[m][1] = bc2; }
    } else {
      int pb = pbc + k0;
#pragma unroll
      for (int m = 0; m < 5; m++) {
        bbl[m][0] = *(const float2*)&brow[pb + 16 * m];
        bbl[m][1] = *(const float2*)&brow[pb + 16 * m + 2];
      }
    }

    bf16x8 bk[4][2];
#pragma unroll
    for (int kt = 0; kt < 4; kt++)
#pragma unroll
      for (int ks = 0; ks < 2; ks++)
        bk[kt][ks] = *(const bf16x8*)&KV[g][(kt * 16 + lr) * 72 + ks * 32 + lq * 8];

    if (more) {
      const unsigned short* Kn = Kb + (long)(2 * i + 2) * 64 * 64;
      const unsigned short* Vn = Vb + (2 * i + 2) * 64;
      kpa = *(const uint4*)&Kn[(long)rs * 64 + fs];
      kpb = *(const uint4*)&Kn[(long)(64 + rs) * 64 + fs];
      vpa = *(const uint4*)&Vn[(long)rs * SEQ + fs];
      vpb = *(const uint4*)&Vn[(long)rs * SEQ + 64 + fs];
    }

    // ---- S^T = K Q^T ----
    f32x4 sacc[4][2];
#pragma unroll
    for (int kt = 0; kt < 4; kt++)
#pragma unroll
      for (int qt = 0; qt < 2; qt++) sacc[kt][qt] = (f32x4){0.f, 0.f, 0.f, 0.f};
#pragma unroll
    for (int ks = 0; ks < 2; ks++)
#pragma unroll
      for (int kt = 0; kt < 4; kt++)
#pragma unroll
        for (int qt = 0; qt < 2; qt++)
          sacc[kt][qt] = __builtin_amdgcn_mfma_f32_16x16x32_bf16(bk[kt][ks], aq[qt][ks], sacc[kt][qt], 0, 0, 0);

    // ---- softmax + PV, P entirely in registers ----
    // P slot layout per lane: e0..3 = kt_even*16 + lq*4 + {0..3}, e4..7 = kt_odd*16 + lq*4 + {0..3}.
    // V LDS layout is pre-permuted to the same k-order -> single b128 per (dt,ktp).
#pragma unroll
    for (int ktp = 0; ktp < 2; ktp++) {
      bf16x8 va8[4];
#pragma unroll
      for (int dt = 0; dt < 4; dt++)
        va8[dt] = *(const bf16x8*)&KV[2 + g][(dt * 16 + lr) * 72 + (ktp * 4 + lq) * 8];
#pragma unroll
      for (int qt = 0; qt < 2; qt++) {
        unsigned int u[4];
#pragma unroll
        for (int kth = 0; kth < 2; kth++) {
          int kt = ktp * 2 + kth;
          int blk = kt - qt + 1;
          float p0 = EXP2(sacc[kt][qt][0] + bbl[blk][0].x);
          float p1 = EXP2(sacc[kt][qt][1] + bbl[blk][0].y);
          float p2 = EXP2(sacc[kt][qt][2] + bbl[blk][1].x);
          float p3 = EXP2(sacc[kt][qt][3] + bbl[blk][1].y);
          rsum[qt] += (p0 + p1) + (p2 + p3);
          u[kth * 2]     = pk_bf16(p0, p1);
          u[kth * 2 + 1] = pk_bf16(p2, p3);
        }
        union { unsigned int uu[4]; bf16x8 v; } pbu;
        pbu.uu[0] = u[0]; pbu.uu[1] = u[1]; pbu.uu[2] = u[2]; pbu.uu[3] = u[3];
#pragma unroll
        for (int dt = 0; dt < 4; dt++)
          accO[dt][qt] = __builtin_amdgcn_mfma_f32_16x16x32_bf16(va8[dt], pbu.v, accO[dt][qt], 0, 0, 0);
      }
    }

    __syncthreads();
    if (more) {
      *(uint4*)&KV[0][rs * 72 + fs] = kpa;
      *(uint4*)&KV[1][rs * 72 + fs] = kpb;
      *(uint2*)&KV[2][vo1] = (uint2){vpa.x, vpa.y};
      *(uint2*)&KV[2][vo2] = (uint2){vpa.z, vpa.w};
      *(uint2*)&KV[3][vo1] = (uint2){vpb.x, vpb.y};
      *(uint2*)&KV[3][vo2] = (uint2){vpb.z, vpb.w};
    }
  }

  // reduce row sums across lq quads (lanes share q = l&15)
#pragma unroll
  for (int qt = 0; qt < 2; qt++) {
    rsum[qt] += __shfl_xor(rsum[qt], 16);
    rsum[qt] += __shfl_xor(rsum[qt], 32);
  }

  // ---- merge group partials via LDS overlay on KV ----
  float* mrg = (float*)&KV[0][0];
  int slot = (wg * 64 + l) * 34;
  if (g == 1) {
    float2* mp = (float2*)&mrg[slot];
    int j = 0;
#pragma unroll
    for (int dt = 0; dt < 4; dt++)
#pragma unroll
      for (int qt = 0; qt < 2; qt++) {
        mp[j++] = (float2){accO[dt][qt][0], accO[dt][qt][1]};
        mp[j++] = (float2){accO[dt][qt][2], accO[dt][qt][3]};
      }
    mp[16] = (float2){rsum[0], rsum[1]};
  }
  __syncthreads();
  if (g == 0) {
    const float2* mp = (const float2*)&mrg[slot];
    int j = 0;
#pragma unroll
    for (int dt = 0; dt < 4; dt++)
#pragma unroll
      for (int qt = 0; qt < 2; qt++) {
        float2 a = mp[j++], b2 = mp[j++];
        accO[dt][qt][0] += a.x;  accO[dt][qt][1] += a.y;
        accO[dt][qt][2] += b2.x; accO[dt][qt][3] += b2.y;
      }
    float2 ls = mp[16];
    float rl0 = 1.0f / (rsum[0] + ls.x);
    float rl1 = 1.0f / (rsum[1] + ls.y);
#pragma unroll
    for (int qt = 0; qt < 2; qt++) {
      float rl = qt ? rl1 : rl0;
      int q = q0 + qw + qt * 16 + lr;
#pragma unroll
      for (int dt = 0; dt < 4; dt++) {
        unsigned int s0 = ((unsigned int)f2bf(accO[dt][qt][1] * rl) << 16) | f2bf(accO[dt][qt][0] * rl);
        unsigned int s1 = ((unsigned int)f2bf(accO[dt][qt][3] * rl) << 16) | f2bf(accO[dt][qt][2] * rl);
        *(uint2*)&O[((long)(b_ * SEQ + q)) * 1024 + h * 64 + dt * 16 + lq * 4] = (uint2){s0, s1};
      }
    }
  }
}

extern "C" void kernel_launch(void* const* d_in, const int* in_sizes, int n_in,
                              void* d_out, int out_size, void* d_ws, size_t ws_size,
                              hipStream_t stream) {
  const float* X   = (const float*)d_in[0];
  const float* Wq  = (const float*)d_in[1];
  const float* Wk  = (const float*)d_in[2];
  const float* Wv  = (const float*)d_in[3];
  const float* Wo  = (const float*)d_in[4];
  const float* tbl = (const float*)d_in[5];

  // compact workspace (40.25 MB): o_ws aliases xbf (dead after QKV gemm)
  unsigned short* wt    = (unsigned short*)d_ws;       // 4 x 1M elems
  unsigned short* xbf   = wt + 4 * 1048576;            // X bf16; later reused as attn O
  unsigned short* q_ws  = xbf + 4194304;
  unsigned short* k_ws  = q_ws + 4194304;
  unsigned short* vt_ws = k_ws + 4194304;              // V^T (B,H,64,S), written by gemm z=2
  float* biasF = (float*)(vt_ws + 4194304);            // 16 x 4096 fp32 (log2e-scaled)
  unsigned short* o_ws  = xbf;

  prep_kernel<<<3088, 256, 0, stream>>>(X, Wq, Wk, Wv, Wo, tbl, xbf, wt, biasF);
  gemm_kernel<<<dim3(32, 8, 3), 256, 0, stream>>>(xbf, wt, q_ws, vt_ws);
  attn_kernel<<<dim3(16, 32), 512, 0, stream>>>(q_ws, k_ws, vt_ws, biasF, o_ws);
  ogemm_kernel<<<dim3(32, 16), 256, 0, stream>>>(o_ws, wt + 3 * 1048576, (float*)d_out);
}

// Round 9
// 196.662 us; speedup vs baseline: 1.0747x; 1.0027x over previous
//
#include <hip/hip_runtime.h>
#include <hip/hip_bf16.h>
#include <math.h>

#define NUM_HEADS 16
#define D_KV 64
#define D_MODEL 1024
#define SEQ 2048
#define BATCH 2
#define LOG2E 1.4426950408889634f

using bf16x8 = __attribute__((ext_vector_type(8))) short;
using bf16x4 = __attribute__((ext_vector_type(4))) short;
using f32x4  = __attribute__((ext_vector_type(4))) float;

__device__ inline unsigned short f2bf(float f) {
  union { float f; unsigned int i; } v; v.f = f;
  unsigned int u = v.i;
  return (unsigned short)((u + 0x7FFFu + ((u >> 16) & 1u)) >> 16);
}
__device__ inline unsigned short f2bf_fast(float f) {
  union { float f; unsigned int i; } v; v.f = f;
  return (unsigned short)((v.i + 0x8000u) >> 16);
}

#if __has_builtin(__builtin_amdgcn_exp2f)
#define EXP2(x) __builtin_amdgcn_exp2f(x)
#else
#define EXP2(x) __expf((x) * 0.6931471805599453f)
#endif

__device__ inline unsigned int pk_bf16(float a, float b) {
#if __has_builtin(__builtin_amdgcn_cvt_pk_bf16_f32)
  auto v = __builtin_amdgcn_cvt_pk_bf16_f32(a, b);
  unsigned int u; __builtin_memcpy(&u, &v, 4);
  return u;
#else
  return ((unsigned int)f2bf_fast(b) << 16) | f2bf_fast(a);
#endif
}

// async global->LDS, 16 B per lane (dest lane-contiguous)
__device__ inline void gld_lds16(const unsigned short* g, unsigned short* l) {
  __builtin_amdgcn_global_load_lds(
      (const __attribute__((address_space(1))) unsigned int*)g,
      (__attribute__((address_space(3))) unsigned int*)l, 16, 0, 0);
}

// ---------------- fused prep: X convert + 4 weight transposes + bias table ----------------
__global__ __launch_bounds__(256) void prep_kernel(const float* __restrict__ X,
                                                   const float* __restrict__ W0,
                                                   const float* __restrict__ W1,
                                                   const float* __restrict__ W2,
                                                   const float* __restrict__ W3,
                                                   const float* __restrict__ tbl,
                                                   unsigned short* __restrict__ xbf,
                                                   unsigned short* __restrict__ wt,
                                                   float* __restrict__ biasF) {
  __shared__ __align__(16) unsigned short T[64][72];
  int bid = blockIdx.x;
  int t = threadIdx.x;
  if (bid < 2048) {
    int i = (bid * 256 + t) * 8;
    __align__(16) unsigned short tmp[8];
#pragma unroll
    for (int e = 0; e < 8; e++) tmp[e] = f2bf(X[i + e]);
    *(uint4*)&xbf[i] = *(uint4*)tmp;
  } else if (bid < 3072) {
    int rem = bid - 2048;
    int z = rem >> 8, tid = rem & 255;
    const float* in = (z == 0) ? W0 : (z == 1) ? W1 : (z == 2) ? W2 : W3;
    unsigned short* o = wt + (long)z * 1048576;
    int r0 = (tid & 15) * 64, c0 = (tid >> 4) * 64;
#pragma unroll
    for (int i = 0; i < 2; i++) {
      int c = t + 256 * i; int r = c >> 3, k8 = (c & 7) * 8;
      const float* src = &in[(long)(r0 + r) * 1024 + c0 + k8];
      __align__(16) unsigned short tmp[8];
#pragma unroll
      for (int e = 0; e < 8; e++) tmp[e] = f2bf(src[e]);
      *(uint4*)&T[r][k8] = *(uint4*)tmp;
    }
    __syncthreads();
#pragma unroll
    for (int i = 0; i < 2; i++) {
      int c = t + 256 * i; int r = c >> 3, k8 = (c & 7) * 8;
      __align__(16) unsigned short tmp[8];
#pragma unroll
      for (int e = 0; e < 8; e++) tmp[e] = T[k8 + e][r];
      *(uint4*)&o[(long)(c0 + r) * 1024 + r0 + k8] = *(uint4*)tmp;
    }
  } else {
    int h = bid - 3072;   // one block per head
#pragma unroll
    for (int ii = 0; ii < 16; ii++) {
      int idx = t + 256 * ii;
      if (idx >= 4095) break;
      int rel = idx - 2047;
      int bucket = (rel > 0) ? 16 : 0;
      int rp = rel < 0 ? -rel : rel;
      int add;
      if (rp < 8) add = rp;
      else {
        int rl = 8 + (int)(logf((float)rp * 0.125f) / logf(16.0f) * 8.0f);
        add = rl < 15 ? rl : 15;
      }
      bucket += add;
      biasF[h * 4096 + idx] = tbl[bucket * 16 + h] * LOG2E;
    }
  }
}

// ---------------- QKV GEMM: C = X(4096x1024) @ Wt(NxK)^T per z, BK=32, dbuf prefetch ----------------
// R12/R13 (validated R5): dbuf staging + counted s_waitcnt vmcnt(4); sched_barrier fences.
// R17: T1 XCD swizzle -- 768%8==0, swz=(bid&7)*96+(bid>>3): each XCD's 96 co-resident
// blocks share z and 3 W-panels (768KB, L2-fit) instead of streaming all 24MB of W.
__global__ __launch_bounds__(256) void gemm_kernel(const unsigned short* __restrict__ X,
                                                   const unsigned short* __restrict__ Wt,
                                                   unsigned short* __restrict__ out_b,
                                                   unsigned short* __restrict__ out_vt) {
  __shared__ __align__(16) unsigned short SMEM[128 * 136];   // loop: As|Bs dbuf 32KB; epilogue: C-tile 34.8KB
  unsigned short* As = SMEM;               // [2 buf][128][32]
  unsigned short* Bs = SMEM + 8192;        // [2 buf][128][32]
  const int K = 1024;
  int bid0 = blockIdx.x + (blockIdx.y << 5) + (blockIdx.z << 8);   // 0..767
  int swz  = (bid0 & 7) * 96 + (bid0 >> 3);                        // bijective
  int m0 = (swz & 31) * 128;
  int n0 = ((swz >> 5) & 7) * 128;
  int zz = swz >> 8;
  const unsigned short* W = Wt + (long)zz * 1048576;
  unsigned short* outq = out_b + (long)zz * 4194304;
  float scale = (zz == 0) ? LOG2E : 1.0f;
  int t = threadIdx.x;
  int w = t >> 6, l = t & 63;
  int wr = (w >> 1) * 64, wc = (w & 1) * 64;
  int lr = l & 15, lq = l >> 4;
  f32x4 acc[4][4];
#pragma unroll
  for (int i = 0; i < 4; i++)
#pragma unroll
    for (int j = 0; j < 4; j++) acc[i][j] = (f32x4){0.f, 0.f, 0.f, 0.f};

  auto STAGE = [&](int buf, int k0) {
    unsigned short* A = As + buf * 4096;
    unsigned short* B = Bs + buf * 4096;
#pragma unroll
    for (int i = 0; i < 2; i++) {
      int c = t + 256 * i;
      int r = c >> 2, kc = (c & 3) * 8;
      gld_lds16(&X[(long)(m0 + r) * K + k0 + kc], &A[c * 8]);
      gld_lds16(&W[(long)(n0 + r) * K + k0 + kc], &B[c * 8]);
    }
  };

  STAGE(0, 0);
  for (int k0 = 0; k0 < K; k0 += 32) {
    int cur = (k0 >> 5) & 1;
    bool more = k0 + 32 < K;
    if (more) {
      STAGE(cur ^ 1, k0 + 32);
      asm volatile("s_waitcnt vmcnt(4)" ::: "memory");   // cur's 4 loads landed; next 4 in flight
    } else {
      asm volatile("s_waitcnt vmcnt(0)" ::: "memory");
    }
    __builtin_amdgcn_s_barrier();
    __builtin_amdgcn_sched_barrier(0);                   // pin ds_reads below the barrier
    const unsigned short* Ab = As + cur * 4096;
    const unsigned short* Bb = Bs + cur * 4096;
    bf16x8 a[4], b[4];
#pragma unroll
    for (int mi = 0; mi < 4; mi++) a[mi] = *(const bf16x8*)&Ab[(wr + mi * 16 + lr) * 32 + lq * 8];
#pragma unroll
    for (int ni = 0; ni < 4; ni++) b[ni] = *(const bf16x8*)&Bb[(wc + ni * 16 + lr) * 32 + lq * 8];
#pragma unroll
    for (int mi = 0; mi < 4; mi++)
#pragma unroll
      for (int ni = 0; ni < 4; ni++)
        acc[mi][ni] = __builtin_amdgcn_mfma_f32_16x16x32_bf16(a[mi], b[ni], acc[mi][ni], 0, 0, 0);
    asm volatile("s_waitcnt lgkmcnt(0)" ::: "memory");   // my reads of buf cur retired
    __builtin_amdgcn_s_barrier();                        // all waves done -> cur re-stageable
    __builtin_amdgcn_sched_barrier(0);                   // pin next STAGE below the barrier
  }

  if (zz == 2) {
    unsigned short* Cs = SMEM;
#pragma unroll
    for (int mi = 0; mi < 4; mi++)
#pragma unroll
      for (int ni = 0; ni < 4; ni++) {
        int nl = wc + ni * 16 + lr;
        int ml = wr + mi * 16 + lq * 4;
        unsigned int s0 = pk_bf16(acc[mi][ni][0], acc[mi][ni][1]);
        unsigned int s1 = pk_bf16(acc[mi][ni][2], acc[mi][ni][3]);
        *(uint2*)&Cs[nl * 136 + ml] = (uint2){s0, s1};
      }
    __syncthreads();
    int b2 = m0 >> 11, sbase = m0 & 2047;
#pragma unroll
    for (int i = 0; i < 8; i++) {
      int c = t + 256 * i;
      int row = c >> 4, ch = c & 15;
      uint4 v = *(const uint4*)&Cs[row * 136 + ch * 8];
      int n = n0 + row, h = n >> 6, d = n & 63;
      *(uint4*)&out_vt[(((long)(b2 * 16 + h) * 64 + d) << 11) + sbase + ch * 8] = v;
    }
  } else {
    unsigned short* Cs = SMEM;
#pragma unroll
    for (int mi = 0; mi < 4; mi++)
#pragma unroll
      for (int ni = 0; ni < 4; ni++)
#pragma unroll
        for (int r = 0; r < 4; r++)
          Cs[(wr + mi * 16 + lq * 4 + r) * 136 + wc + ni * 16 + lr] = f2bf(acc[mi][ni][r] * scale);
    __syncthreads();
    int b2 = m0 >> 11, sbase = m0 & 2047;
#pragma unroll
    for (int i = 0; i < 8; i++) {
      int c = t + 256 * i;
      int row = c >> 4, ch = c & 15;
      uint4 v = *(const uint4*)&Cs[row * 136 + ch * 8];
      int n = n0 + ch * 8, h = n >> 6, d = n & 63;
      *(uint4*)&outq[((long)(b2 * 16 + h) * 2048 + sbase + row) * 64 + d] = v;
    }
  }
}

// ---------------- out-projection GEMM: 128x64 tiles, BK=64, 512 blocks (2/CU), dbuf ----------------
// R16 tile + R17 XCD swizzle (512%8==0, swz=(bid&7)*64+(bid>>3)).
__global__ __launch_bounds__(256) void ogemm_kernel(const unsigned short* __restrict__ X,
                                                    const unsigned short* __restrict__ W,
                                                    float* __restrict__ out) {
  __shared__ __align__(16) unsigned char SMEM[57344];  // staging dbuf 48KB (pad->2 blk/CU) / epilogue 17.4KB
  unsigned short* As = (unsigned short*)SMEM;          // [2 buf][2 ks][128][32]
  unsigned short* Bs = As + 16384;                     // [2 buf][2 ks][64][32]
  float* Csf = (float*)SMEM;                           // [64][68]
  const int K = 1024;
  int bid0 = blockIdx.x + (blockIdx.y << 5);           // 0..511
  int swz  = (bid0 & 7) * 64 + (bid0 >> 3);            // bijective
  int m0 = (swz & 31) * 128;
  int n0 = (swz >> 5) * 64;
  int t = threadIdx.x;
  int w = t >> 6, l = t & 63;
  int wr = (w >> 1) * 64, wc = (w & 1) * 32;
  int lr = l & 15, lq = l >> 4;
  f32x4 acc[4][2];
#pragma unroll
  for (int i = 0; i < 4; i++)
#pragma unroll
    for (int j = 0; j < 2; j++) acc[i][j] = (f32x4){0.f, 0.f, 0.f, 0.f};

  auto STAGE = [&](int buf, int k0) {
    unsigned short* A = As + buf * 8192;
    unsigned short* B = Bs + buf * 4096;
#pragma unroll
    for (int i = 0; i < 4; i++) {
      int c = t + 256 * i;                       // A: c*8 == p*4096 + r*32 + kc
      int p = c >> 9, r = (c >> 2) & 127, kc = (c & 3) * 8;
      gld_lds16(&X[(long)(m0 + r) * K + k0 + p * 32 + kc], &A[c * 8]);
    }
#pragma unroll
    for (int i = 0; i < 2; i++) {
      int c = t + 256 * i;                       // B: c*8 == p*2048 + r*32 + kc
      int p = c >> 8, r = (c >> 2) & 63, kc = (c & 3) * 8;
      gld_lds16(&W[(long)(n0 + r) * K + k0 + p * 32 + kc], &B[c * 8]);
    }
  };

  STAGE(0, 0);
  for (int k0 = 0; k0 < K; k0 += 64) {
    int cur = (k0 >> 6) & 1;
    bool more = k0 + 64 < K;
    if (more) {
      STAGE(cur ^ 1, k0 + 64);
      asm volatile("s_waitcnt vmcnt(6)" ::: "memory");   // cur's 6 landed; next 6 in flight
    } else {
      asm volatile("s_waitcnt vmcnt(0)" ::: "memory");
    }
    __builtin_amdgcn_s_barrier();
    __builtin_amdgcn_sched_barrier(0);
    const unsigned short* Ab = As + cur * 8192;
    const unsigned short* Bb = Bs + cur * 4096;
    bf16x8 a[4][2], b[2][2];
#pragma unroll
    for (int ks = 0; ks < 2; ks++) {
#pragma unroll
      for (int mi = 0; mi < 4; mi++) a[mi][ks] = *(const bf16x8*)&Ab[ks * 4096 + (wr + mi * 16 + lr) * 32 + lq * 8];
#pragma unroll
      for (int ni = 0; ni < 2; ni++) b[ni][ks] = *(const bf16x8*)&Bb[ks * 2048 + (wc + ni * 16 + lr) * 32 + lq * 8];
    }
#pragma unroll
    for (int ks = 0; ks < 2; ks++)
#pragma unroll
      for (int mi = 0; mi < 4; mi++)
#pragma unroll
        for (int ni = 0; ni < 2; ni++)
          acc[mi][ni] = __builtin_amdgcn_mfma_f32_16x16x32_bf16(a[mi][ks], b[ni][ks], acc[mi][ni], 0, 0, 0);
    asm volatile("s_waitcnt lgkmcnt(0)" ::: "memory");
    __builtin_amdgcn_s_barrier();
    __builtin_amdgcn_sched_barrier(0);
  }

  // epilogue: two 64-row half-tiles through fp32 LDS
#pragma unroll
  for (int p = 0; p < 2; p++) {
    if (p) __syncthreads();
    if ((w >> 1) == p) {
#pragma unroll
      for (int mi = 0; mi < 4; mi++)
#pragma unroll
        for (int ni = 0; ni < 2; ni++)
#pragma unroll
          for (int r = 0; r < 4; r++)
            Csf[(mi * 16 + lq * 4 + r) * 68 + wc + ni * 16 + lr] = acc[mi][ni][r];
    }
    __syncthreads();
#pragma unroll
    for (int i = 0; i < 4; i++) {
      int c = t + 256 * i;
      int row = c >> 4, ch = c & 15;
      float4 v = *(const float4*)&Csf[row * 68 + ch * 4];
      *(float4*)&out[(long)(m0 + p * 64 + row) * 1024 + n0 + ch * 4] = v;
    }
  }
}

// ---------------- flash attention: 512-thread blocks, intra-block K-split ----------------
// R9: P stays in registers (permuted-k contraction); bias splat for saturated buckets.
// R11: V stored in LDS with the P k-permutation BAKED IN (conflict-free b128 V reads).
// R17 (this round): bias LDS table DELETED -- non-splat iters (~3/16) read btabF
// directly from global (L2-hot, 256KB): per-lane base bgl = btabF + 2047-q0-qw-lr+4lq;
// element (blk,j) at bgl[k0-16+16blk+j], idx range (1766,2328) -- no clamp needed.
// 20 scalar dword loads w/ imm offsets, issued before the QK MFMA block -> hidden.
// Frees 17.4KB LDS (occupancy unchanged: grid 512 = 2/CU is grid-bound).
__global__ __launch_bounds__(512) void attn_kernel(const unsigned short* __restrict__ Q,
                                                   const unsigned short* __restrict__ Km,
                                                   const unsigned short* __restrict__ Vt,
                                                   const float* __restrict__ biasF,
                                                   unsigned short* __restrict__ O) {
  __shared__ __align__(16) unsigned short KV[4][4608];  // [0,1]=K par0/1, [2,3]=V par0/1 (64x72)
  int q0 = blockIdx.x * 128;
  int bh = blockIdx.y;
  int b_ = bh >> 4, h = bh & 15;
  const unsigned short* Qb = Q  + (long)bh * SEQ * 64;
  const unsigned short* Kb = Km + (long)bh * SEQ * 64;
  const unsigned short* Vb = Vt + (long)bh * 64 * SEQ;
  const float* btabF = biasF + h * 4096;
  int t = threadIdx.x;
  int w = t >> 6, l = t & 63;
  int g = w >> 2, wg = w & 3;
  int lr = l & 15, lq = l >> 4;
  int qw = wg * 32;

  // saturated-bucket constants (rel=+2047 -> bucket 31, rel=-2047 -> bucket 15)
  float bL = btabF[0], bH = btabF[4094];

  // per-lane global bias base: bgl[i] == btabF[2047 - (q0+qw+lr) + 4*lq + i]
  const float* bgl = btabF + (2047 - q0 - qw - lr + lq * 4);

  bf16x8 aq[2][2];
#pragma unroll
  for (int qt = 0; qt < 2; qt++)
#pragma unroll
    for (int ks = 0; ks < 2; ks++)
      aq[qt][ks] = *(const bf16x8*)&Qb[(long)(q0 + qw + qt * 16 + lr) * 64 + ks * 32 + lq * 8];

  int rs = t >> 3, fs = (t & 7) * 8;

  // permuted V write offsets (loop-invariant): thread's 8 contiguous k split into
  // two uint2 groups matching the in-register P k-order.
  int ktpS = (fs >> 5) & 1;
  int q2 = (fs >> 3) & 3;
  int caS = ktpS * 4 + (q2 & 1) * 2;
  int offS = (q2 >> 1) * 4;
  int vo1 = rs * 72 + caS * 8 + offS;
  int vo2 = vo1 + 8;

  uint4 kpa = *(const uint4*)&Kb[(long)rs * 64 + fs];
  uint4 kpb = *(const uint4*)&Kb[(long)(64 + rs) * 64 + fs];
  uint4 vpa = *(const uint4*)&Vb[(long)rs * SEQ + fs];
  uint4 vpb = *(const uint4*)&Vb[(long)rs * SEQ + 64 + fs];
  *(uint4*)&KV[0][rs * 72 + fs] = kpa;
  *(uint4*)&KV[1][rs * 72 + fs] = kpb;
  *(uint2*)&KV[2][vo1] = (uint2){vpa.x, vpa.y};
  *(uint2*)&KV[2][vo2] = (uint2){vpa.z, vpa.w};
  *(uint2*)&KV[3][vo1] = (uint2){vpb.x, vpb.y};
  *(uint2*)&KV[3][vo2] = (uint2){vpb.z, vpb.w};

  f32x4 accO[4][2];   // [dt][qt], O^T C-tiles (row=d, col=q)
  float rsum[2] = {0.f, 0.f};
#pragma unroll
  for (int qt = 0; qt < 2; qt++)
#pragma unroll
    for (int dt = 0; dt < 4; dt++) accO[dt][qt] = (f32x4){0.f, 0.f, 0.f, 0.f};

  for (int i = 0; i < 16; i++) {
    __syncthreads();
    int k0 = (2 * i + g) * 64;
    bool more = i < 15;

    // ---- bias values: global reads (L2-hot) in ~3/16 iters; splat otherwise ----
    float bblf[5][4];
    int dq = k0 - q0;
    if (dq >= 218 || dq <= -154) {
      float bc = (dq >= 218) ? bH : bL;
#pragma unroll
      for (int m = 0; m < 5; m++)
#pragma unroll
        for (int j = 0; j < 4; j++) bblf[m][j] = bc;
    } else {
      const float* bb = bgl + (k0 - 16);
#pragma unroll
      for (int m = 0; m < 5; m++)
#pragma unroll
        for (int j = 0; j < 4; j++) bblf[m][j] = bb[16 * m + j];
    }

    bf16x8 bk[4][2];
#pragma unroll
    for (int kt = 0; kt < 4; kt++)
#pragma unroll
      for (int ks = 0; ks < 2; ks++)
        bk[kt][ks] = *(const bf16x8*)&KV[g][(kt * 16 + lr) * 72 + ks * 32 + lq * 8];

    if (more) {
      const unsigned short* Kn = Kb + (long)(2 * i + 2) * 64 * 64;
      const unsigned short* Vn = Vb + (2 * i + 2) * 64;
      kpa = *(const uint4*)&Kn[(long)rs * 64 + fs];
      kpb = *(const uint4*)&Kn[(long)(64 + rs) * 64 + fs];
      vpa = *(const uint4*)&Vn[(long)rs * SEQ + fs];
      vpb = *(const uint4*)&Vn[(long)rs * SEQ + 64 + fs];
    }

    // ---- S^T = K Q^T ----
    f32x4 sacc[4][2];
#pragma unroll
    for (int kt = 0; kt < 4; kt++)
#pragma unroll
      for (int qt = 0; qt < 2; qt++) sacc[kt][qt] = (f32x4){0.f, 0.f, 0.f, 0.f};
#pragma unroll
    for (int ks = 0; ks < 2; ks++)
#pragma unroll
      for (int kt = 0; kt < 4; kt++)
#pragma unroll
        for (int qt = 0; qt < 2; qt++)
          sacc[kt][qt] = __builtin_amdgcn_mfma_f32_16x16x32_bf16(bk[kt][ks], aq[qt][ks], sacc[kt][qt], 0, 0, 0);

    // ---- softmax + PV, P entirely in registers ----
    // P slot layout per lane: e0..3 = kt_even*16 + lq*4 + {0..3}, e4..7 = kt_odd*16 + lq*4 + {0..3}.
    // V LDS layout is pre-permuted to the same k-order -> single b128 per (dt,ktp).
#pragma unroll
    for (int ktp = 0; ktp < 2; ktp++) {
      bf16x8 va8[4];
#pragma unroll
      for (int dt = 0; dt < 4; dt++)
        va8[dt] = *(const bf16x8*)&KV[2 + g][(dt * 16 + lr) * 72 + (ktp * 4 + lq) * 8];
#pragma unroll
      for (int qt = 0; qt < 2; qt++) {
        unsigned int u[4];
#pragma unroll
        for (int kth = 0; kth < 2; kth++) {
          int kt = ktp * 2 + kth;
          int blk = kt - qt + 1;
          float p0 = EXP2(sacc[kt][qt][0] + bblf[blk][0]);
          float p1 = EXP2(sacc[kt][qt][1] + bblf[blk][1]);
          float p2 = EXP2(sacc[kt][qt][2] + bblf[blk][2]);
          float p3 = EXP2(sacc[kt][qt][3] + bblf[blk][3]);
          rsum[qt] += (p0 + p1) + (p2 + p3);
          u[kth * 2]     = pk_bf16(p0, p1);
          u[kth * 2 + 1] = pk_bf16(p2, p3);
        }
        union { unsigned int uu[4]; bf16x8 v; } pbu;
        pbu.uu[0] = u[0]; pbu.uu[1] = u[1]; pbu.uu[2] = u[2]; pbu.uu[3] = u[3];
#pragma unroll
        for (int dt = 0; dt < 4; dt++)
          accO[dt][qt] = __builtin_amdgcn_mfma_f32_16x16x32_bf16(va8[dt], pbu.v, accO[dt][qt], 0, 0, 0);
      }
    }

    __syncthreads();
    if (more) {
      *(uint4*)&KV[0][rs * 72 + fs] = kpa;
      *(uint4*)&KV[1][rs * 72 + fs] = kpb;
      *(uint2*)&KV[2][vo1] = (uint2){vpa.x, vpa.y};
      *(uint2*)&KV[2][vo2] = (uint2){vpa.z, vpa.w};
      *(uint2*)&KV[3][vo1] = (uint2){vpb.x, vpb.y};
      *(uint2*)&KV[3][vo2] = (uint2){vpb.z, vpb.w};
    }
  }

  // reduce row sums across lq quads (lanes share q = l&15)
#pragma unroll
  for (int qt = 0; qt < 2; qt++) {
    rsum[qt] += __shfl_xor(rsum[qt], 16);
    rsum[qt] += __shfl_xor(rsum[qt], 32);
  }

  // ---- merge group partials via LDS overlay on KV ----
  float* mrg = (float*)&KV[0][0];
  int slot = (wg * 64 + l) * 34;
  if (g == 1) {
    float2* mp = (float2*)&mrg[slot];
    int j = 0;
#pragma unroll
    for (int dt = 0; dt < 4; dt++)
#pragma unroll
      for (int qt = 0; qt < 2; qt++) {
        mp[j++] = (float2){accO[dt][qt][0], accO[dt][qt][1]};
        mp[j++] = (float2){accO[dt][qt][2], accO[dt][qt][3]};
      }
    mp[16] = (float2){rsum[0], rsum[1]};
  }
  __syncthreads();
  if (g == 0) {
    const float2* mp = (const float2*)&mrg[slot];
    int j = 0;
#pragma unroll
    for (int dt = 0; dt < 4; dt++)
#pragma unroll
      for (int qt = 0; qt < 2; qt++) {
        float2 a = mp[j++], b2 = mp[j++];
        accO[dt][qt][0] += a.x;  accO[dt][qt][1] += a.y;
        accO[dt][qt][2] += b2.x; accO[dt][qt][3] += b2.y;
      }
    float2 ls = mp[16];
    float rl0 = 1.0f / (rsum[0] + ls.x);
    float rl1 = 1.0f / (rsum[1] + ls.y);
#pragma unroll
    for (int qt = 0; qt < 2; qt++) {
      float rl = qt ? rl1 : rl0;
      int q = q0 + qw + qt * 16 + lr;
#pragma unroll
      for (int dt = 0; dt < 4; dt++) {
        unsigned int s0 = ((unsigned int)f2bf(accO[dt][qt][1] * rl) << 16) | f2bf(accO[dt][qt][0] * rl);
        unsigned int s1 = ((unsigned int)f2bf(accO[dt][qt][3] * rl) << 16) | f2bf(accO[dt][qt][2] * rl);
        *(uint2*)&O[((long)(b_ * SEQ + q)) * 1024 + h * 64 + dt * 16 + lq * 4] = (uint2){s0, s1};
      }
    }
  }
}

extern "C" void kernel_launch(void* const* d_in, const int* in_sizes, int n_in,
                              void* d_out, int out_size, void* d_ws, size_t ws_size,
                              hipStream_t stream) {
  const float* X   = (const float*)d_in[0];
  const float* Wq  = (const float*)d_in[1];
  const float* Wk  = (const float*)d_in[2];
  const float* Wv  = (const float*)d_in[3];
  const float* Wo  = (const float*)d_in[4];
  const float* tbl = (const float*)d_in[5];

  // compact workspace (40.25 MB): o_ws aliases xbf (dead after QKV gemm)
  unsigned short* wt    = (unsigned short*)d_ws;       // 4 x 1M elems
  unsigned short* xbf   = wt + 4 * 1048576;            // X bf16; later reused as attn O
  unsigned short* q_ws  = xbf + 4194304;
  unsigned short* k_ws  = q_ws + 4194304;
  unsigned short* vt_ws = k_ws + 4194304;              // V^T (B,H,64,S), written by gemm z=2
  float* biasF = (float*)(vt_ws + 4194304);            // 16 x 4096 fp32 (log2e-scaled)
  unsigned short* o_ws  = xbf;

  prep_kernel<<<3088, 256, 0, stream>>>(X, Wq, Wk, Wv, Wo, tbl, xbf, wt, biasF);
  gemm_kernel<<<dim3(32, 8, 3), 256, 0, stream>>>(xbf, wt, q_ws, vt_ws);
  attn_kernel<<<dim3(16, 32), 512, 0, stream>>>(q_ws, k_ws, vt_ws, biasF, o_ws);
  ogemm_kernel<<<dim3(32, 16), 256, 0, stream>>>(o_ws, wt + 3 * 1048576, (float*)d_out);
}